// Round 1
// baseline (5548.362 us; speedup 1.0000x reference)
//
#include <hip/hip_runtime.h>
#include <math.h>

#define B 8
#define D 1024
#define T 4096
#define Q 8
#define K 1024
#define CD 32

// ---------------- ws layout (bytes) ----------------
// z_e   f64 [B][CD][T]  : 8 MB      @ 0
// cbn   f64 [Q][K][CD]  : 2 MB      @ ZE_B
// cbn2  f64 [Q][K]      : 64 KB     @ ZE_B + CBN_B
// idx   i32 [B][T]      : 128 KB    @ ...
#define ZE_B   ((size_t)B * CD * T * 8)
#define CBN_B  ((size_t)Q * K * CD * 8)
#define CBN2_B ((size_t)Q * K * 8)

__global__ void k_zero_losses(float* __restrict__ loss) {
    if (threadIdx.x < Q) loss[threadIdx.x] = 0.0f;
}

// Normalize codebooks in fp64: cbn = cb * rsqrt(sum(cb^2)+eps), cbn2 = sum(cbn^2)
__global__ __launch_bounds__(256) void k_norm_cb(const float* __restrict__ cb,
                                                 double* __restrict__ cbn,
                                                 double* __restrict__ cbn2) {
    int i = blockIdx.x * 256 + threadIdx.x;      // code id over Q*K
    const float* c = cb + (size_t)i * CD;
    double v[CD];
    double ss = 0.0;
#pragma unroll
    for (int j = 0; j < CD; ++j) { v[j] = (double)c[j]; ss += v[j] * v[j]; }
    double s = 1.0 / sqrt(ss + 1e-12);
    double n2 = 0.0;
    double* o = cbn + (size_t)i * CD;
#pragma unroll
    for (int j = 0; j < CD; ++j) { double vn = v[j] * s; o[j] = vn; n2 += vn * vn; }
    cbn2[i] = n2;
}

// z_e[b,c,t] = sum_d Win[q,c,d] * res[b,d,t] + b_in[q,c]   (fp64 accumulate)
__global__ __launch_bounds__(128) void k_inproj(const float* __restrict__ res,
                                                const float* __restrict__ Win,
                                                const float* __restrict__ b_in,
                                                double* __restrict__ z_e, int q) {
    const int t = blockIdx.x * 128 + threadIdx.x;
    const int b = blockIdx.y;
    __shared__ double wsh[CD][64];                 // 16 KB chunk: 32 c x 64 d
    double acc[CD];
    const float* bi = b_in + q * CD;
#pragma unroll
    for (int c = 0; c < CD; ++c) acc[c] = (double)bi[c];
    const float* rb = res + ((size_t)b * D) * T + t;
    const float* wq = Win + ((size_t)q * CD) * D;
    for (int d0 = 0; d0 < D; d0 += 64) {
        __syncthreads();
        for (int i = threadIdx.x; i < CD * 64; i += 128) {
            int c = i >> 6, dl = i & 63;
            wsh[c][dl] = (double)wq[c * D + d0 + dl];
        }
        __syncthreads();
#pragma unroll 4
        for (int dl = 0; dl < 64; ++dl) {
            double v = (double)rb[(size_t)(d0 + dl) * T];
#pragma unroll
            for (int c = 0; c < CD; ++c) acc[c] = fma(wsh[c][dl], v, acc[c]);
        }
    }
    double* zb = z_e + ((size_t)b * CD) * T + t;
#pragma unroll
    for (int c = 0; c < CD; ++c) zb[(size_t)c * T] = acc[c];
}

// argmin over K codes (fp64 distances), write idx (int + float), accumulate loss
__global__ __launch_bounds__(128) void k_argmin(const double* __restrict__ z_e,
                                                const double* __restrict__ cbn,
                                                const double* __restrict__ cbn2,
                                                const float* __restrict__ cb,
                                                int* __restrict__ idxp,
                                                float* __restrict__ idx_f,
                                                float* __restrict__ loss, int q) {
    const int t = blockIdx.x * 128 + threadIdx.x;
    const int b = blockIdx.y;
    __shared__ double csh[256][CD];                // 64 KB codebook chunk
    __shared__ double n2sh[256];

    double zn[CD];
    const double* zb = z_e + ((size_t)b * CD) * T + t;
    double ss = 0.0;
#pragma unroll
    for (int c = 0; c < CD; ++c) { zn[c] = zb[(size_t)c * T]; ss += zn[c] * zn[c]; }
    double rnorm = sqrt(ss + 1e-12);
    double s = 1.0 / rnorm;
    double A = 0.0;
#pragma unroll
    for (int c = 0; c < CD; ++c) { zn[c] *= s; A += zn[c] * zn[c]; }

    double best = 1e300;
    int bi = 0;
    for (int k0 = 0; k0 < K; k0 += 256) {
        __syncthreads();
        const double* src = cbn + (((size_t)q * K + k0) * CD);
        for (int i = threadIdx.x; i < 256 * CD; i += 128) csh[i >> 5][i & 31] = src[i];
        for (int i = threadIdx.x; i < 256; i += 128) n2sh[i] = cbn2[(size_t)q * K + k0 + i];
        __syncthreads();
        for (int k = 0; k < 256; k += 2) {
            double d0 = 0.0, d1 = 0.0;
            const double* c0 = &csh[k][0];
            const double* c1 = &csh[k + 1][0];
#pragma unroll
            for (int c = 0; c < CD; ++c) {
                d0 = fma(zn[c], c0[c], d0);
                d1 = fma(zn[c], c1[c], d1);
            }
            double dist0 = (A - 2.0 * d0) + n2sh[k];
            double dist1 = (A - 2.0 * d1) + n2sh[k + 1];
            if (dist0 < best) { best = dist0; bi = k0 + k; }
            if (dist1 < best) { best = dist1; bi = k0 + k + 1; }
        }
    }

    // loss partial: sum_c (z_e - cb_raw[bi])^2   (reconstruct raw z = zn*rnorm)
    const float* cq = cb + (((size_t)q * K + bi) * CD);
    double sq = 0.0;
#pragma unroll
    for (int c = 0; c < CD; ++c) {
        double diff = zn[c] * rnorm - (double)cq[c];
        sq = fma(diff, diff, sq);
    }
#pragma unroll
    for (int off = 32; off > 0; off >>= 1) sq += __shfl_down(sq, off);
    if ((threadIdx.x & 63) == 0)
        atomicAdd(&loss[q], (float)(sq * (1.25 / (double)((size_t)B * CD * T))));

    idxp[b * T + t] = bi;
    idx_f[(size_t)q * B * T + (size_t)b * T + t] = (float)bi;
}

// res_out[b,d,t] = res_in[b,d,t] - (sum_c Wout[q,d,c]*cb[q,idx,c] + b_out[q,d])
__global__ __launch_bounds__(256) void k_outproj(const float* __restrict__ rin,
                                                 float* __restrict__ rout,
                                                 const float* __restrict__ Wout,
                                                 const float* __restrict__ bo,
                                                 const float* __restrict__ cb,
                                                 const int* __restrict__ idxp, int q) {
    const int t = blockIdx.x * 256 + threadIdx.x;
    const int b = blockIdx.y;
    const int d0 = blockIdx.z * 256;
    __shared__ double wsh[256][CD];                // 64 KB
    __shared__ double bsh[256];

    int k = idxp[b * T + t];
    double zq[CD];
    const float* cq = cb + (((size_t)q * K + k) * CD);
#pragma unroll
    for (int c = 0; c < CD; ++c) zq[c] = (double)cq[c];

    const float* wsrc = Wout + (((size_t)q * D + d0) * CD);
    for (int i = threadIdx.x; i < 256 * CD; i += 256) wsh[i >> 5][i & 31] = (double)wsrc[i];
    bsh[threadIdx.x] = (double)bo[q * D + d0 + threadIdx.x];
    __syncthreads();

    const size_t base = ((size_t)b * D + d0) * T + t;
    for (int dl = 0; dl < 256; ++dl) {
        double sacc = bsh[dl];
#pragma unroll
        for (int c = 0; c < CD; ++c) sacc = fma(wsh[dl][c], zq[c], sacc);
        size_t o = base + (size_t)dl * T;
        rout[o] = (float)((double)rin[o] - sacc);
    }
}

// out0 = x - residual_final (residual lives in out[0..B*D*T))
__global__ __launch_bounds__(256) void k_final(const float4* __restrict__ x,
                                               float4* __restrict__ out, int n4) {
    int i = blockIdx.x * 256 + threadIdx.x;
    const int stride = gridDim.x * 256;
    for (; i < n4; i += stride) {
        float4 a = x[i];
        float4 r = out[i];
        out[i] = make_float4(a.x - r.x, a.y - r.y, a.z - r.z, a.w - r.w);
    }
}

extern "C" void kernel_launch(void* const* d_in, const int* in_sizes, int n_in,
                              void* d_out, int out_size, void* d_ws, size_t ws_size,
                              hipStream_t stream) {
    const float* x    = (const float*)d_in[0];
    const float* Win  = (const float*)d_in[1];
    const float* b_in = (const float*)d_in[2];
    const float* Wout = (const float*)d_in[3];
    const float* b_out= (const float*)d_in[4];
    const float* cb   = (const float*)d_in[5];

    float* out   = (float*)d_out;
    float* res   = out;                                  // residual in-place in out[0..BDT)
    float* idx_f = out + (size_t)B * D * T;
    float* loss  = idx_f + (size_t)Q * B * T;

    char* w = (char*)d_ws;
    double* z_e  = (double*)w;
    double* cbn  = (double*)(w + ZE_B);
    double* cbn2 = (double*)(w + ZE_B + CBN_B);
    int*    idxp = (int*)(w + ZE_B + CBN_B + CBN2_B);

    k_zero_losses<<<1, 64, 0, stream>>>(loss);
    k_norm_cb<<<(Q * K) / 256, 256, 0, stream>>>(cb, cbn, cbn2);

    for (int q = 0; q < Q; ++q) {
        const float* rin = (q == 0) ? x : res;
        k_inproj<<<dim3(T / 128, B), 128, 0, stream>>>(rin, Win, b_in, z_e, q);
        k_argmin<<<dim3(T / 128, B), 128, 0, stream>>>(z_e, cbn, cbn2, cb, idxp, idx_f, loss, q);
        k_outproj<<<dim3(T / 256, B, D / 256), 256, 0, stream>>>(rin, res, Wout, b_out, cb, idxp, q);
    }

    k_final<<<4096, 256, 0, stream>>>((const float4*)x, (float4*)out, (B * D * T) / 4);
}

// Round 2
// 4746.015 us; speedup vs baseline: 1.1691x; 1.1691x over previous
//
#include <hip/hip_runtime.h>
#include <math.h>

#define B 8
#define D 1024
#define T 4096
#define Q 8
#define K 1024
#define CD 32
#define BT (B * T)

// ---------------- scratch layout inside d_out (bytes) ----------------
// All scratch is dead before k_final overwrites floats [0 .. B*D*T).
// out0  f32 [B][D][T]            @ 0          (final output, written last)
// idx_f f32 [Q][B][T]            @ 134217728  (output 1)
// loss  f32 [Q]                  @ 135266304  (output 2)
#define OFF_PART  ((size_t)0)          // f64 [8][B][CD][T]  -> only 8 d-chunks of current stage: [8][B][CD][T]? see below
// part: f64 [NDC][B][CD][T], NDC=8  => 8*8*32*4096*8 = 64MB?  -- too big; NDC=8 with chunk 128:
// 8 chunks * 8 * 32 * 4096 * 8B = 64MB. Keep: fits (out region is 128MB, idx_f starts at 128MB).
#define NDC 8
#define PART_BYTES ((size_t)NDC * B * CD * T * 8)          // 67108864 (64MB)
#define OFF_MT    (PART_BYTES)                              // f64 [8][8][K][CD] 16MB
#define OFF_CBN   (OFF_MT + (size_t)64 * K * CD * 8)        // f64 [8][K][CD] 2MB
#define OFF_N264  (OFF_CBN + (size_t)Q * K * CD * 8)        // f64 [8][K] 64KB
#define OFF_NT    (OFF_N264 + (size_t)Q * K * 8)            // f64 [8][8][CD][CD] 512KB
#define OFF_BEFF  (OFF_NT + (size_t)64 * CD * CD * 8)       // f64 [8][CD] 2KB
#define OFF_C32   (OFF_BEFF + (size_t)Q * CD * 8)           // f32 [8][K][CD] 1MB
#define OFF_N232  (OFF_C32 + (size_t)Q * K * CD * 4)        // f32 [8][K] 32KB
// end = 64MB + 16MB + 2MB + 64KB + 512KB + 2KB + 1MB + 32KB ~= 83.6MB < 128MB  OK

__global__ void k_zero_losses(float* __restrict__ loss) {
    if (threadIdx.x < Q) loss[threadIdx.x] = 0.0f;
}

// Normalize codebooks fp64 (identical numerics to round-1) + fp32 copies for prefilter.
__global__ __launch_bounds__(256) void k_norm(const float* __restrict__ cb,
                                              double* __restrict__ cbn64,
                                              double* __restrict__ n264,
                                              float* __restrict__ cbn32,
                                              float* __restrict__ n232) {
    int i = blockIdx.x * 256 + threadIdx.x;   // 0..Q*K-1
    const float* c = cb + (size_t)i * CD;
    double v[CD];
    double ss = 0.0;
#pragma unroll
    for (int j = 0; j < CD; ++j) { v[j] = (double)c[j]; ss += v[j] * v[j]; }
    double s = 1.0 / sqrt(ss + 1e-12);
    double n2 = 0.0;
    double* o = cbn64 + (size_t)i * CD;
    float* o32 = cbn32 + (size_t)i * CD;
#pragma unroll
    for (int j = 0; j < CD; ++j) {
        double vn = v[j] * s;
        o[j] = vn; o32[j] = (float)vn; n2 += vn * vn;
    }
    n264[i] = n2; n232[i] = (float)n2;
}

// N[q][j][c][c'] = sum_d Win_q[c,d] * Wout_j[d,c']   (fp64)
__global__ __launch_bounds__(256) void k_prep_N(const float* __restrict__ Win,
                                                const float* __restrict__ Wout,
                                                double* __restrict__ Ntab) {
    const int q = blockIdx.x >> 3, j = blockIdx.x & 7;
    __shared__ float a_sh[CD][128];
    __shared__ float b_sh[128][CD];
    double acc[4] = {0.0, 0.0, 0.0, 0.0};
    for (int d0 = 0; d0 < D; d0 += 128) {
        __syncthreads();
        for (int i = threadIdx.x; i < CD * 128; i += 256) {
            int cc = i >> 7, dl = i & 127;
            a_sh[cc][dl] = Win[((size_t)q * CD + cc) * D + d0 + dl];
        }
        for (int i = threadIdx.x; i < 128 * CD; i += 256) {
            int dl = i >> 5, cc = i & 31;
            b_sh[dl][cc] = Wout[((size_t)j * D + d0 + dl) * CD + cc];
        }
        __syncthreads();
        for (int dl = 0; dl < 128; ++dl) {
#pragma unroll
            for (int r = 0; r < 4; ++r) {
                int i = r * 256 + threadIdx.x;
                acc[r] = fma((double)a_sh[i >> 5][dl], (double)b_sh[dl][i & 31], acc[r]);
            }
        }
    }
#pragma unroll
    for (int r = 0; r < 4; ++r) {
        int i = r * 256 + threadIdx.x;
        Ntab[((size_t)(q * 8 + j) * CD + (i >> 5)) * CD + (i & 31)] = acc[r];
    }
}

// M[q][j][k][c] = sum_c' N[q][j][c][c'] * cb_j[k][c']   (fp64)
__global__ __launch_bounds__(256) void k_prep_M(const float* __restrict__ cb,
                                                const double* __restrict__ Ntab,
                                                double* __restrict__ Mt) {
    const int q = blockIdx.z, j = blockIdx.y;
    const int k = blockIdx.x * 256 + threadIdx.x;
    __shared__ double nsh[CD][CD];
    for (int i = threadIdx.x; i < CD * CD; i += 256)
        nsh[i >> 5][i & 31] = Ntab[(size_t)(q * 8 + j) * CD * CD + i];
    __syncthreads();
    double cv[CD];
    const float* cr = cb + ((size_t)j * K + k) * CD;
#pragma unroll
    for (int c = 0; c < CD; ++c) cv[c] = (double)cr[c];
    double* mo = Mt + (((size_t)(q * 8 + j) * K + k) * CD);
#pragma unroll
    for (int c = 0; c < CD; ++c) {
        double a = 0.0;
#pragma unroll
        for (int cp = 0; cp < CD; ++cp) a = fma(nsh[c][cp], cv[cp], a);
        mo[c] = a;
    }
}

// beff[q][c] = b_in[q][c] - sum_d Win_q[c][d] * (sum_{j<q} b_out[j][d])
__global__ __launch_bounds__(256) void k_prep_beff(const float* __restrict__ Win,
                                                   const float* __restrict__ b_in,
                                                   const float* __restrict__ b_out,
                                                   double* __restrict__ beff) {
    const int c = blockIdx.x, q = blockIdx.y;
    __shared__ double red[256];
    double p = 0.0;
    for (int d = threadIdx.x; d < D; d += 256) {
        double bp = 0.0;
        for (int j = 0; j < q; ++j) bp += (double)b_out[j * D + d];
        p = fma((double)Win[((size_t)q * CD + c) * D + d], bp, p);
    }
    red[threadIdx.x] = p;
    __syncthreads();
    for (int s = 128; s > 0; s >>= 1) {
        if (threadIdx.x < s) red[threadIdx.x] += red[threadIdx.x + s];
        __syncthreads();
    }
    if (threadIdx.x == 0) beff[q * CD + c] = (double)b_in[q * CD + c] - red[0];
}

// part[dc][b][c][t] = sum_{d in chunk dc} Win_q[c][d] * x[b][d][t]   (fp64)
// grid (T/512, B, NDC), 256 thr, 2 t per thread.
__global__ __launch_bounds__(256) void k_gemmA(const float* __restrict__ x,
                                               const float* __restrict__ Win,
                                               double* __restrict__ part, int q) {
    const int ta = blockIdx.x * 512 + threadIdx.x;   // t and t+256
    const int b = blockIdx.y;
    const int dc = blockIdx.z;
    const int d0 = dc * (D / NDC);                   // chunk of 128
    __shared__ double wsh[CD][D / NDC];              // 32KB
    const float* wq = Win + ((size_t)q * CD) * D + d0;
    for (int i = threadIdx.x; i < CD * (D / NDC); i += 256) {
        int c = i >> 7, dl = i & 127;
        wsh[c][dl] = (double)wq[c * D + dl];
    }
    __syncthreads();
    double acca[CD], accb[CD];
#pragma unroll
    for (int c = 0; c < CD; ++c) { acca[c] = 0.0; accb[c] = 0.0; }
    const float* xa = x + ((size_t)b * D + d0) * T + ta;
#pragma unroll 2
    for (int dl = 0; dl < D / NDC; ++dl) {
        double va = (double)xa[(size_t)dl * T];
        double vb = (double)xa[(size_t)dl * T + 256];
#pragma unroll
        for (int c = 0; c < CD; ++c) {
            acca[c] = fma(wsh[c][dl], va, acca[c]);
            accb[c] = fma(wsh[c][dl], vb, accb[c]);
        }
    }
    double* po = part + (((size_t)dc * B + b) * CD) * T + ta;
#pragma unroll
    for (int c = 0; c < CD; ++c) {
        po[(size_t)c * T] = acca[c];
        po[(size_t)c * T + 256] = accb[c];
    }
}

// Reconstruct z_e (fp64, fixed op order everywhere for determinism).
__device__ __forceinline__ void reconstruct_z(const double* __restrict__ part,
                                              const double* __restrict__ Mt,
                                              const double* __restrict__ beff,
                                              const float* __restrict__ idx_f,
                                              int q, int b, int t, double z[CD]) {
    const size_t bt = (size_t)b * T + t;
    const size_t dcs = (size_t)B * CD * T;
#pragma unroll
    for (int c = 0; c < CD; ++c) {
        const double* p = part + ((size_t)b * CD + c) * T + t;
        double s = p[0];
#pragma unroll
        for (int dc = 1; dc < NDC; ++dc) s += p[dc * dcs];
        z[c] = s + beff[q * CD + c];
    }
    for (int j = 0; j < q; ++j) {
        int kj = (int)idx_f[(size_t)j * BT + bt];
        const double* m = Mt + (((size_t)(q * 8 + j) * K + kj) * CD);
#pragma unroll
        for (int c = 0; c < CD; ++c) z[c] -= m[c];
    }
}

// One block = 128 t values; 4 k-chunk groups of 128 threads scan 256 codes each
// in fp32; group 0 merges, rescans in fp64 when fp32 gap < 1e-4, computes loss.
#define KCG 4
#define TB 128
__global__ __launch_bounds__(512) void k_argmin(const double* __restrict__ part,
                                                const double* __restrict__ Mt,
                                                const double* __restrict__ beff,
                                                const double* __restrict__ cbn64,
                                                const double* __restrict__ n264,
                                                const float* __restrict__ cbn32,
                                                const float* __restrict__ n232,
                                                const float* __restrict__ cb,
                                                float* __restrict__ idx_f,
                                                float* __restrict__ loss, int q) {
    const int tl = threadIdx.x & (TB - 1);
    const int kc = threadIdx.x >> 7;
    const int t = blockIdx.x * TB + tl;
    const int b = blockIdx.y;
    const size_t bt = (size_t)b * T + t;

    __shared__ float csh[KCG][256][CD];   // 128KB
    __shared__ float nsh[KCG][256];
    __shared__ float md1[KCG][TB], md2[KCG][TB];
    __shared__ int   mi1[KCG][TB];

    {
        const float4* src = (const float4*)(cbn32 + ((size_t)q * K + kc * 256) * CD);
        float4* dst = (float4*)&csh[kc][0][0];
        for (int i = tl; i < 256 * CD / 4; i += TB) dst[i] = src[i];
        for (int i = tl; i < 256; i += TB) nsh[kc][i] = n232[q * K + kc * 256 + i];
    }

    double z[CD];
    reconstruct_z(part, Mt, beff, idx_f, q, b, t, z);
    double ss = 0.0;
#pragma unroll
    for (int c = 0; c < CD; ++c) ss += z[c] * z[c];
    double s = 1.0 / sqrt(ss + 1e-12);
    float znf[CD];
    float a2 = 0.0f;
#pragma unroll
    for (int c = 0; c < CD; ++c) { znf[c] = (float)(z[c] * s); a2 = fmaf(znf[c], znf[c], a2); }

    __syncthreads();

    float d1 = 1e30f, d2 = 1e30f; int i1 = 0;
    for (int k = 0; k < 256; ++k) {
        float dot = 0.0f;
#pragma unroll
        for (int c = 0; c < CD; ++c) dot = fmaf(znf[c], csh[kc][k][c], dot);
        float dist = fmaf(-2.0f, dot, a2) + nsh[kc][k];
        if (dist < d1) { d2 = d1; d1 = dist; i1 = kc * 256 + k; }
        else if (dist < d2) { d2 = dist; }
    }
    md1[kc][tl] = d1; md2[kc][tl] = d2; mi1[kc][tl] = i1;
    __syncthreads();

    if (kc == 0) {
        float g1 = 1e30f, g2 = 1e30f; int gi = 0;
        for (int c4 = 0; c4 < KCG; ++c4) {
            float a = md1[c4][tl], bb = md2[c4][tl]; int ii = mi1[c4][tl];
            if (a < g1) { g2 = fminf(g1, bb); g1 = a; gi = ii; }
            else { g2 = fminf(g2, fminf(a, bb)); }
        }
        int bi = gi;
        if (g2 - g1 < 1e-4f) {
            // fp64 rescan: replicate round-1's exact formula and order
            double zn[CD]; double A = 0.0;
#pragma unroll
            for (int c = 0; c < CD; ++c) { zn[c] = z[c] * s; A += zn[c] * zn[c]; }
            double best = 1e300; int bj = 0;
            const double* cq = cbn64 + (size_t)q * K * CD;
            const double* nq = n264 + (size_t)q * K;
            for (int k = 0; k < K; ++k) {
                double dot = 0.0;
#pragma unroll
                for (int c = 0; c < CD; ++c) dot = fma(zn[c], cq[(size_t)k * CD + c], dot);
                double dist = (A - 2.0 * dot) + nq[k];
                if (dist < best) { best = dist; bj = k; }
            }
            bi = bj;
        }
        const float* cr = cb + ((size_t)q * K + bi) * CD;
        double sq = 0.0;
#pragma unroll
        for (int c = 0; c < CD; ++c) {
            double diff = z[c] - (double)cr[c];
            sq = fma(diff, diff, sq);
        }
#pragma unroll
        for (int off = 32; off > 0; off >>= 1) sq += __shfl_down(sq, off);
        if ((tl & 63) == 0)
            atomicAdd(&loss[q], (float)(sq * (1.25 / (double)((size_t)B * CD * T))));
        idx_f[(size_t)q * BT + bt] = (float)bi;
    }
}

// out[b][d][t] = sum_j ( Wout_j[d,:] . cb_j[idx_j[b,t],:] + bo_j[d] )
// grid (T/32, B, D/256), 256 thr (one d each), 32 t per block, LDS transpose for
// coalesced stores.
#define FT 32
__global__ __launch_bounds__(256) void k_final(const float* __restrict__ Wout,
                                               const float* __restrict__ bo,
                                               const float* __restrict__ cb,
                                               const float* __restrict__ idx_f,
                                               float* __restrict__ out) {
    const int t0 = blockIdx.x * FT;
    const int b = blockIdx.y;
    const int d0 = blockIdx.z * 256;
    __shared__ int ki[Q][FT];
    __shared__ float csh[Q][FT][CD];          // 32KB
    __shared__ float tile[256][FT + 1];       // 33KB

    if (threadIdx.x < Q * FT) {
        int j = threadIdx.x >> 5, tt = threadIdx.x & 31;
        ki[j][tt] = (int)idx_f[(size_t)j * BT + (size_t)b * T + t0 + tt];
    }
    __syncthreads();
    for (int i = threadIdx.x; i < Q * FT * CD / 4; i += 256) {
        int fi = i * 4;
        int j = fi >> 10;
        int tt = (fi >> 5) & 31;
        int c4 = (fi & 31) >> 2;
        ((float4*)&csh[j][tt][0])[c4] =
            ((const float4*)(cb + ((size_t)j * K + ki[j][tt]) * CD))[c4];
    }
    __syncthreads();

    const int d = d0 + threadIdx.x;
    float acc[FT];
    {
        float bs = 0.0f;
#pragma unroll
        for (int j = 0; j < Q; ++j) bs += bo[j * D + d];
#pragma unroll
        for (int tt = 0; tt < FT; ++tt) acc[tt] = bs;
    }
    for (int j = 0; j < Q; ++j) {
        float w[CD];
        const float4* wp = (const float4*)(Wout + ((size_t)j * D + d) * CD);
#pragma unroll
        for (int r = 0; r < CD / 4; ++r) {
            float4 v = wp[r];
            w[r * 4 + 0] = v.x; w[r * 4 + 1] = v.y; w[r * 4 + 2] = v.z; w[r * 4 + 3] = v.w;
        }
#pragma unroll
        for (int tt = 0; tt < FT; ++tt) {
            float dot = 0.0f;
#pragma unroll
            for (int c = 0; c < CD; ++c) dot = fmaf(w[c], csh[j][tt][c], dot);
            acc[tt] += dot;
        }
    }
#pragma unroll
    for (int tt = 0; tt < FT; ++tt) tile[threadIdx.x][tt] = acc[tt];
    __syncthreads();
    for (int r = 0; r < FT; ++r) {
        int i = r * 256 + threadIdx.x;
        int dl = i >> 5, tl2 = i & 31;
        out[((size_t)b * D + d0 + dl) * T + t0 + tl2] = tile[dl][tl2];
    }
}

extern "C" void kernel_launch(void* const* d_in, const int* in_sizes, int n_in,
                              void* d_out, int out_size, void* d_ws, size_t ws_size,
                              hipStream_t stream) {
    const float* x     = (const float*)d_in[0];
    const float* Win   = (const float*)d_in[1];
    const float* b_in  = (const float*)d_in[2];
    const float* Wout  = (const float*)d_in[3];
    const float* b_out = (const float*)d_in[4];
    const float* cb    = (const float*)d_in[5];

    float* out0  = (float*)d_out;
    float* idx_f = out0 + (size_t)B * D * T;
    float* loss  = idx_f + (size_t)Q * BT;

    char* sc = (char*)d_out;   // scratch region: floats [0 .. B*D*T), dead before k_final
    double* part  = (double*)(sc + OFF_PART);
    double* Mt    = (double*)(sc + OFF_MT);
    double* cbn64 = (double*)(sc + OFF_CBN);
    double* n264  = (double*)(sc + OFF_N264);
    double* Ntab  = (double*)(sc + OFF_NT);
    double* beff  = (double*)(sc + OFF_BEFF);
    float*  cbn32 = (float*)(sc + OFF_C32);
    float*  n232  = (float*)(sc + OFF_N232);

    k_zero_losses<<<1, 64, 0, stream>>>(loss);
    k_norm<<<(Q * K) / 256, 256, 0, stream>>>(cb, cbn64, n264, cbn32, n232);
    k_prep_N<<<64, 256, 0, stream>>>(Win, Wout, Ntab);
    k_prep_M<<<dim3(K / 256, 8, 8), 256, 0, stream>>>(cb, Ntab, Mt);
    k_prep_beff<<<dim3(CD, Q), 256, 0, stream>>>(Win, b_in, b_out, beff);

    for (int q = 0; q < Q; ++q) {
        k_gemmA<<<dim3(T / 512, B, NDC), 256, 0, stream>>>(x, Win, part, q);
        k_argmin<<<dim3(T / TB, B), 512, 0, stream>>>(part, Mt, beff, cbn64, n264,
                                                      cbn32, n232, cb, idx_f, loss, q);
    }

    k_final<<<dim3(T / FT, B, D / 256), 256, 0, stream>>>(Wout, b_out, cb, idx_f, out0);
}

// Round 3
// 4522.678 us; speedup vs baseline: 1.2268x; 1.0494x over previous
//
#include <hip/hip_runtime.h>
#include <math.h>

#define B 8
#define D 1024
#define T 4096
#define Q 8
#define K 1024
#define CD 32
#define BT (B * T)

// ---------------- scratch layout inside d_out (bytes) ----------------
// d_out floats [0 .. B*D*T) are scratch until k_final (the last kernel) writes them.
// idx_f output lives at +134217728, loss at +135266304 — never used as scratch.
#define OFF_Z0   ((size_t)0)                          // f64 [Q][B][CD][T]   64 MB
#define OFF_MT   (OFF_Z0 + (size_t)Q * B * CD * T * 8)  // f64 [8][8][K][CD] 16 MB
#define OFF_CBN  (OFF_MT + (size_t)64 * K * CD * 8)     // f64 [Q][K][CD]     2 MB
#define OFF_N264 (OFF_CBN + (size_t)Q * K * CD * 8)     // f64 [Q][K]        64 KB
#define OFF_NT   (OFF_N264 + (size_t)Q * K * 8)         // f64 [64][CD][CD] 512 KB
#define OFF_BEFF (OFF_NT + (size_t)64 * CD * CD * 8)    // f64 [Q][CD]        2 KB
#define OFF_C32  (OFF_BEFF + (size_t)Q * CD * 8)        // f32 [Q][K][CD]     1 MB
#define OFF_N232 (OFF_C32 + (size_t)Q * K * CD * 4)     // f32 [Q][K]        32 KB
#define OFF_W64  (OFF_N232 + (size_t)Q * K * 4)         // f64 [Q][CD][D]     2 MB
#define OFF_IDXI (OFF_W64 + (size_t)Q * CD * D * 8)     // i32 [Q][BT]        1 MB
// total ~86.6 MB < 128 MB

__global__ void k_zero_losses(float* __restrict__ loss) {
    if (threadIdx.x < Q) loss[threadIdx.x] = 0.0f;
}

// Normalize codebooks fp64 + fp32 copies for the prefilter.
__global__ __launch_bounds__(256) void k_norm(const float* __restrict__ cb,
                                              double* __restrict__ cbn64,
                                              double* __restrict__ n264,
                                              float* __restrict__ cbn32,
                                              float* __restrict__ n232) {
    int i = blockIdx.x * 256 + threadIdx.x;   // 0..Q*K-1
    const float* c = cb + (size_t)i * CD;
    double v[CD];
    double ss = 0.0;
#pragma unroll
    for (int j = 0; j < CD; ++j) { v[j] = (double)c[j]; ss += v[j] * v[j]; }
    double s = 1.0 / sqrt(ss + 1e-12);
    double n2 = 0.0;
    double* o = cbn64 + (size_t)i * CD;
    float* o32 = cbn32 + (size_t)i * CD;
#pragma unroll
    for (int j = 0; j < CD; ++j) {
        double vn = v[j] * s;
        o[j] = vn; o32[j] = (float)vn; n2 += vn * vn;
    }
    n264[i] = n2; n232[i] = (float)n2;
}

// Win -> fp64 copy (so gemmZ weight loads are scalar f64, no per-FMA cvt)
__global__ __launch_bounds__(256) void k_cvtW(const float* __restrict__ Win,
                                              double* __restrict__ Win64) {
    int i = blockIdx.x * 256 + threadIdx.x;
    Win64[i] = (double)Win[i];
}

// N[q][j][c][c'] = sum_d Win_q[c,d] * Wout_j[d,c']   (fp64)
__global__ __launch_bounds__(256) void k_prep_N(const float* __restrict__ Win,
                                                const float* __restrict__ Wout,
                                                double* __restrict__ Ntab) {
    const int q = blockIdx.x >> 3, j = blockIdx.x & 7;
    __shared__ float a_sh[CD][128];
    __shared__ float b_sh[128][CD];
    double acc[4] = {0.0, 0.0, 0.0, 0.0};
    for (int d0 = 0; d0 < D; d0 += 128) {
        __syncthreads();
        for (int i = threadIdx.x; i < CD * 128; i += 256) {
            int cc = i >> 7, dl = i & 127;
            a_sh[cc][dl] = Win[((size_t)q * CD + cc) * D + d0 + dl];
        }
        for (int i = threadIdx.x; i < 128 * CD; i += 256) {
            int dl = i >> 5, cc = i & 31;
            b_sh[dl][cc] = Wout[((size_t)j * D + d0 + dl) * CD + cc];
        }
        __syncthreads();
        for (int dl = 0; dl < 128; ++dl) {
#pragma unroll
            for (int r = 0; r < 4; ++r) {
                int i = r * 256 + threadIdx.x;
                acc[r] = fma((double)a_sh[i >> 5][dl], (double)b_sh[dl][i & 31], acc[r]);
            }
        }
    }
#pragma unroll
    for (int r = 0; r < 4; ++r) {
        int i = r * 256 + threadIdx.x;
        Ntab[((size_t)(q * 8 + j) * CD + (i >> 5)) * CD + (i & 31)] = acc[r];
    }
}

// M[q][j][k][c] = sum_c' N[q][j][c][c'] * cb_j[k][c']   (fp64)
__global__ __launch_bounds__(256) void k_prep_M(const float* __restrict__ cb,
                                                const double* __restrict__ Ntab,
                                                double* __restrict__ Mt) {
    const int q = blockIdx.z, j = blockIdx.y;
    const int k = blockIdx.x * 256 + threadIdx.x;
    __shared__ double nsh[CD][CD];
    for (int i = threadIdx.x; i < CD * CD; i += 256)
        nsh[i >> 5][i & 31] = Ntab[(size_t)(q * 8 + j) * CD * CD + i];
    __syncthreads();
    double cv[CD];
    const float* cr = cb + ((size_t)j * K + k) * CD;
#pragma unroll
    for (int c = 0; c < CD; ++c) cv[c] = (double)cr[c];
    double* mo = Mt + (((size_t)(q * 8 + j) * K + k) * CD);
#pragma unroll
    for (int c = 0; c < CD; ++c) {
        double a = 0.0;
#pragma unroll
        for (int cp = 0; cp < CD; ++cp) a = fma(nsh[c][cp], cv[cp], a);
        mo[c] = a;
    }
}

// beff[q][c] = b_in[q][c] - sum_d Win_q[c][d] * (sum_{j<q} b_out[j][d])
__global__ __launch_bounds__(256) void k_prep_beff(const float* __restrict__ Win,
                                                   const float* __restrict__ b_in,
                                                   const float* __restrict__ b_out,
                                                   double* __restrict__ beff) {
    const int c = blockIdx.x, q = blockIdx.y;
    __shared__ double red[256];
    double p = 0.0;
    for (int d = threadIdx.x; d < D; d += 256) {
        double bp = 0.0;
        for (int j = 0; j < q; ++j) bp += (double)b_out[j * D + d];
        p = fma((double)Win[((size_t)q * CD + c) * D + d], bp, p);
    }
    red[threadIdx.x] = p;
    __syncthreads();
    for (int s = 128; s > 0; s >>= 1) {
        if (threadIdx.x < s) red[threadIdx.x] += red[threadIdx.x + s];
        __syncthreads();
    }
    if (threadIdx.x == 0) beff[q * CD + c] = (double)b_in[q * CD + c] - red[0];
}

// z0[q][b][c][t] = beff[q][c] + sum_d Win_q[c][d] * x[b][d][t]  (fp64, all stages)
// Weights are block-uniform -> scalar loads; no LDS. Block swizzle keeps the 8
// q-variants of one (b,t)-chunk on the same XCD so the 8x re-read of x hits L2.
__global__ __launch_bounds__(256) void k_gemmZ(const float* __restrict__ x,
                                               const double* __restrict__ Win64,
                                               const double* __restrict__ beff,
                                               double* __restrict__ z0) {
    // N = Q*B*(T/256) = 1024 blocks. h%8 = XCD (round-robin heuristic).
    int h = blockIdx.x;
    int u = h >> 3, r = h & 7;
    int q = u & 7;
    int m = r + 8 * (u >> 3);      // 0..127: (b, t-chunk) group, constant per XCD batch
    int b = m >> 4;
    int tc = m & 15;
    int t = tc * 256 + threadIdx.x;

    const double* w = Win64 + (size_t)q * CD * D;     // uniform
    const double* be = beff + q * CD;                 // uniform
    const float* xb = x + (size_t)b * D * T + t;

    double acc[CD];
#pragma unroll
    for (int c = 0; c < CD; ++c) acc[c] = be[c];

    for (int d0 = 0; d0 < D; d0 += 8) {
        double xv[8];
#pragma unroll
        for (int i = 0; i < 8; ++i) xv[i] = (double)xb[(size_t)(d0 + i) * T];
#pragma unroll
        for (int c = 0; c < CD; ++c) {
            const double* wc = w + (size_t)c * D + d0;
#pragma unroll
            for (int i = 0; i < 8; ++i) acc[c] = fma(wc[i], xv[i], acc[c]);
        }
    }
    double* zo = z0 + (((size_t)q * B + b) * CD) * T + t;
#pragma unroll
    for (int c = 0; c < CD; ++c) zo[(size_t)c * T] = acc[c];
}

// z[c] = z0[q][b][c][t] - sum_{j<q} M[q][j][idx_j][c]   (fp64, fixed order)
__device__ __forceinline__ void reconstruct_z(const double* __restrict__ z0,
                                              const double* __restrict__ Mt,
                                              const int* __restrict__ idxi,
                                              int q, int b, int t, double z[CD]) {
    const size_t bt = (size_t)b * T + t;
#pragma unroll
    for (int c = 0; c < CD; ++c)
        z[c] = z0[(((size_t)q * B + b) * CD + c) * T + t];
    for (int j = 0; j < q; ++j) {
        int kj = idxi[j * BT + bt];
        const double* m = Mt + (((size_t)(q * 8 + j) * K + kj) * CD);
#pragma unroll
        for (int c = 0; c < CD; ++c) z[c] -= m[c];
    }
}

// fp32 prefilter over K, fp64 rescan when top-2 gap < 1e-4 (proven structure).
#define KCG 4
#define TB 128
__global__ __launch_bounds__(512) void k_argmin(const double* __restrict__ z0,
                                                const double* __restrict__ Mt,
                                                const double* __restrict__ cbn64,
                                                const double* __restrict__ n264,
                                                const float* __restrict__ cbn32,
                                                const float* __restrict__ n232,
                                                const float* __restrict__ cb,
                                                int* __restrict__ idxi,
                                                float* __restrict__ idx_f,
                                                float* __restrict__ loss, int q) {
    const int tl = threadIdx.x & (TB - 1);
    const int kc = threadIdx.x >> 7;
    const int t = blockIdx.x * TB + tl;
    const int b = blockIdx.y;
    const size_t bt = (size_t)b * T + t;

    __shared__ float csh[KCG][256][CD];   // 128KB
    __shared__ float nsh[KCG][256];
    __shared__ float md1[KCG][TB], md2[KCG][TB];
    __shared__ int   mi1[KCG][TB];

    {
        const float4* src = (const float4*)(cbn32 + ((size_t)q * K + kc * 256) * CD);
        float4* dst = (float4*)&csh[kc][0][0];
        for (int i = tl; i < 256 * CD / 4; i += TB) dst[i] = src[i];
        for (int i = tl; i < 256; i += TB) nsh[kc][i] = n232[q * K + kc * 256 + i];
    }

    double z[CD];
    reconstruct_z(z0, Mt, idxi, q, b, t, z);
    double ss = 0.0;
#pragma unroll
    for (int c = 0; c < CD; ++c) ss += z[c] * z[c];
    double s = 1.0 / sqrt(ss + 1e-12);
    float znf[CD];
    float a2 = 0.0f;
#pragma unroll
    for (int c = 0; c < CD; ++c) { znf[c] = (float)(z[c] * s); a2 = fmaf(znf[c], znf[c], a2); }

    __syncthreads();

    float d1 = 1e30f, d2 = 1e30f; int i1 = 0;
    for (int k = 0; k < 256; ++k) {
        float dot = 0.0f;
#pragma unroll
        for (int c = 0; c < CD; ++c) dot = fmaf(znf[c], csh[kc][k][c], dot);
        float dist = fmaf(-2.0f, dot, a2) + nsh[kc][k];
        if (dist < d1) { d2 = d1; d1 = dist; i1 = kc * 256 + k; }
        else if (dist < d2) { d2 = dist; }
    }
    md1[kc][tl] = d1; md2[kc][tl] = d2; mi1[kc][tl] = i1;
    __syncthreads();

    if (kc == 0) {
        float g1 = 1e30f, g2 = 1e30f; int gi = 0;
        for (int c4 = 0; c4 < KCG; ++c4) {
            float a = md1[c4][tl], bb = md2[c4][tl]; int ii = mi1[c4][tl];
            if (a < g1) { g2 = fminf(g1, bb); g1 = a; gi = ii; }
            else { g2 = fminf(g2, fminf(a, bb)); }
        }
        int bi = gi;
        if (g2 - g1 < 1e-4f) {
            double zn[CD]; double A = 0.0;
#pragma unroll
            for (int c = 0; c < CD; ++c) { zn[c] = z[c] * s; A += zn[c] * zn[c]; }
            double best = 1e300; int bj = 0;
            const double* cq = cbn64 + (size_t)q * K * CD;
            const double* nq = n264 + (size_t)q * K;
            for (int k = 0; k < K; ++k) {
                double dot = 0.0;
#pragma unroll
                for (int c = 0; c < CD; ++c) dot = fma(zn[c], cq[(size_t)k * CD + c], dot);
                double dist = (A - 2.0 * dot) + nq[k];
                if (dist < best) { best = dist; bj = k; }
            }
            bi = bj;
        }
        const float* cr = cb + ((size_t)q * K + bi) * CD;
        double sq = 0.0;
#pragma unroll
        for (int c = 0; c < CD; ++c) {
            double diff = z[c] - (double)cr[c];
            sq = fma(diff, diff, sq);
        }
#pragma unroll
        for (int off = 32; off > 0; off >>= 1) sq += __shfl_down(sq, off);
        if ((tl & 63) == 0)
            atomicAdd(&loss[q], (float)(sq * (1.25 / (double)((size_t)B * CD * T))));
        idxi[q * BT + bt] = bi;
        idx_f[(size_t)q * BT + bt] = (float)bi;
    }
}

// out[b][d][t] = sum_j ( Wout_j[d,:].cb_j[idx_j[b,t],:] ) + sum_j bo_j[d]
// Codes are block-uniform -> readfirstlane + s_load; inner loop is pure
// v_fma(vgpr, sgpr, vgpr). LDS only for the store transpose.
#define FT 32
__global__ __launch_bounds__(256) void k_final(const float* __restrict__ Wout,
                                               const float* __restrict__ bo,
                                               const float* __restrict__ cb,
                                               const float* __restrict__ idx_f,
                                               float* __restrict__ out) {
    const int t0 = blockIdx.x * FT;
    const int b = blockIdx.y;
    const int d0 = blockIdx.z * 256;
    __shared__ int ki[Q][FT];
    __shared__ float tile[256][FT + 1];

    if (threadIdx.x < Q * FT) {
        int j = threadIdx.x >> 5, tt = threadIdx.x & 31;
        ki[j][tt] = (int)idx_f[(size_t)j * BT + (size_t)b * T + t0 + tt];
    }
    __syncthreads();

    const int d = d0 + threadIdx.x;
    float acc[FT];
    {
        float bs = 0.0f;
#pragma unroll
        for (int j = 0; j < Q; ++j) bs += bo[j * D + d];
#pragma unroll
        for (int tt = 0; tt < FT; ++tt) acc[tt] = bs;
    }
    for (int j = 0; j < Q; ++j) {
        float w[CD];
        const float4* wp = (const float4*)(Wout + ((size_t)j * D + d) * CD);
#pragma unroll
        for (int r = 0; r < CD / 4; ++r) {
            float4 v = wp[r];
            w[r * 4 + 0] = v.x; w[r * 4 + 1] = v.y; w[r * 4 + 2] = v.z; w[r * 4 + 3] = v.w;
        }
        for (int tg = 0; tg < FT; tg += 4) {
            const float* c0 = cb + ((size_t)j * K + __builtin_amdgcn_readfirstlane(ki[j][tg + 0])) * CD;
            const float* c1 = cb + ((size_t)j * K + __builtin_amdgcn_readfirstlane(ki[j][tg + 1])) * CD;
            const float* c2 = cb + ((size_t)j * K + __builtin_amdgcn_readfirstlane(ki[j][tg + 2])) * CD;
            const float* c3 = cb + ((size_t)j * K + __builtin_amdgcn_readfirstlane(ki[j][tg + 3])) * CD;
#pragma unroll
            for (int c = 0; c < CD; ++c) {
                acc[tg + 0] = fmaf(w[c], c0[c], acc[tg + 0]);
                acc[tg + 1] = fmaf(w[c], c1[c], acc[tg + 1]);
                acc[tg + 2] = fmaf(w[c], c2[c], acc[tg + 2]);
                acc[tg + 3] = fmaf(w[c], c3[c], acc[tg + 3]);
            }
        }
    }
#pragma unroll
    for (int tt = 0; tt < FT; ++tt) tile[threadIdx.x][tt] = acc[tt];
    __syncthreads();
    for (int r = 0; r < FT; ++r) {
        int i = r * 256 + threadIdx.x;
        int dl = i >> 5, tl2 = i & 31;
        out[((size_t)b * D + d0 + dl) * T + t0 + tl2] = tile[dl][tl2];
    }
}

extern "C" void kernel_launch(void* const* d_in, const int* in_sizes, int n_in,
                              void* d_out, int out_size, void* d_ws, size_t ws_size,
                              hipStream_t stream) {
    const float* x     = (const float*)d_in[0];
    const float* Win   = (const float*)d_in[1];
    const float* b_in  = (const float*)d_in[2];
    const float* Wout  = (const float*)d_in[3];
    const float* b_out = (const float*)d_in[4];
    const float* cb    = (const float*)d_in[5];

    float* out0  = (float*)d_out;
    float* idx_f = out0 + (size_t)B * D * T;
    float* loss  = idx_f + (size_t)Q * BT;

    char* sc = (char*)d_out;   // scratch region: dead before k_final overwrites it
    double* z0    = (double*)(sc + OFF_Z0);
    double* Mt    = (double*)(sc + OFF_MT);
    double* cbn64 = (double*)(sc + OFF_CBN);
    double* n264  = (double*)(sc + OFF_N264);
    double* Ntab  = (double*)(sc + OFF_NT);
    double* beff  = (double*)(sc + OFF_BEFF);
    float*  cbn32 = (float*)(sc + OFF_C32);
    float*  n232  = (float*)(sc + OFF_N232);
    double* Win64 = (double*)(sc + OFF_W64);
    int*    idxi  = (int*)(sc + OFF_IDXI);

    k_zero_losses<<<1, 64, 0, stream>>>(loss);
    k_norm<<<(Q * K) / 256, 256, 0, stream>>>(cb, cbn64, n264, cbn32, n232);
    k_cvtW<<<(Q * CD * D) / 256, 256, 0, stream>>>(Win, Win64);
    k_prep_N<<<64, 256, 0, stream>>>(Win, Wout, Ntab);
    k_prep_M<<<dim3(K / 256, 8, 8), 256, 0, stream>>>(cb, Ntab, Mt);
    k_prep_beff<<<dim3(CD, Q), 256, 0, stream>>>(Win, b_in, b_out, beff);

    k_gemmZ<<<Q * B * (T / 256), 256, 0, stream>>>(x, Win64, beff, z0);

    for (int q = 0; q < Q; ++q) {
        k_argmin<<<dim3(T / TB, B), 512, 0, stream>>>(z0, Mt, cbn64, n264,
                                                      cbn32, n232, cb, idxi, idx_f, loss, q);
    }

    k_final<<<dim3(T / FT, B, D / 256), 256, 0, stream>>>(Wout, b_out, cb, idx_f, out0);
}

// Round 4
// 3755.713 us; speedup vs baseline: 1.4773x; 1.2042x over previous
//
#include <hip/hip_runtime.h>
#include <math.h>

#define B 8
#define D 1024
#define T 4096
#define Q 8
#define K 1024
#define CD 32
#define BT (B * T)

// ---------------- scratch layout inside d_out (bytes) ----------------
// d_out floats [0 .. B*D*T) are scratch until k_gemm_final (last kernel) writes them.
// k_gemm_final reads ONLY inputs + idxi (in d_ws) -> no overlap hazard.
#define OFF_Z0   ((size_t)0)                            // f64 [Q][B][CD][T]  64 MB
#define OFF_MT   (OFF_Z0 + (size_t)Q * B * CD * T * 8)  // f64 [8][8][K][CD]  16 MB
#define OFF_CBN  (OFF_MT + (size_t)64 * K * CD * 8)     // f64 [Q][K][CD]      2 MB
#define OFF_N264 (OFF_CBN + (size_t)Q * K * CD * 8)     // f64 [Q][K]         64 KB
#define OFF_NT   (OFF_N264 + (size_t)Q * K * 8)         // f64 [64][CD][CD]  512 KB
#define OFF_BEFF (OFF_NT + (size_t)64 * CD * CD * 8)    // f64 [Q][CD]         2 KB
#define OFF_C32  (OFF_BEFF + (size_t)Q * CD * 8)        // f32 [Q][K][CD]      1 MB
#define OFF_N232 (OFF_C32 + (size_t)Q * K * CD * 4)     // f32 [Q][K]         32 KB
#define OFF_W64  (OFF_N232 + (size_t)Q * K * 4)         // f64 [Q][CD][D]      2 MB
// idxi i32 [Q][BT] lives in d_ws @ 0 (1 MB)

__global__ void k_zero_losses(float* __restrict__ loss) {
    if (threadIdx.x < Q) loss[threadIdx.x] = 0.0f;
}

// Normalize codebooks fp64 + fp32 copies for the prefilter.
__global__ __launch_bounds__(256) void k_norm(const float* __restrict__ cb,
                                              double* __restrict__ cbn64,
                                              double* __restrict__ n264,
                                              float* __restrict__ cbn32,
                                              float* __restrict__ n232) {
    int i = blockIdx.x * 256 + threadIdx.x;   // 0..Q*K-1
    const float* c = cb + (size_t)i * CD;
    double v[CD];
    double ss = 0.0;
#pragma unroll
    for (int j = 0; j < CD; ++j) { v[j] = (double)c[j]; ss += v[j] * v[j]; }
    double s = 1.0 / sqrt(ss + 1e-12);
    double n2 = 0.0;
    double* o = cbn64 + (size_t)i * CD;
    float* o32 = cbn32 + (size_t)i * CD;
#pragma unroll
    for (int j = 0; j < CD; ++j) {
        double vn = v[j] * s;
        o[j] = vn; o32[j] = (float)vn; n2 += vn * vn;
    }
    n264[i] = n2; n232[i] = (float)n2;
}

// Win -> fp64 copy
__global__ __launch_bounds__(256) void k_cvtW(const float* __restrict__ Win,
                                              double* __restrict__ Win64) {
    int i = blockIdx.x * 256 + threadIdx.x;
    Win64[i] = (double)Win[i];
}

// N[q][j][c][c'] = sum_d Win_q[c,d] * Wout_j[d,c']   (fp64)
__global__ __launch_bounds__(256) void k_prep_N(const float* __restrict__ Win,
                                                const float* __restrict__ Wout,
                                                double* __restrict__ Ntab) {
    const int q = blockIdx.x >> 3, j = blockIdx.x & 7;
    __shared__ float a_sh[CD][128];
    __shared__ float b_sh[128][CD];
    double acc[4] = {0.0, 0.0, 0.0, 0.0};
    for (int d0 = 0; d0 < D; d0 += 128) {
        __syncthreads();
        for (int i = threadIdx.x; i < CD * 128; i += 256) {
            int cc = i >> 7, dl = i & 127;
            a_sh[cc][dl] = Win[((size_t)q * CD + cc) * D + d0 + dl];
        }
        for (int i = threadIdx.x; i < 128 * CD; i += 256) {
            int dl = i >> 5, cc = i & 31;
            b_sh[dl][cc] = Wout[((size_t)j * D + d0 + dl) * CD + cc];
        }
        __syncthreads();
        for (int dl = 0; dl < 128; ++dl) {
#pragma unroll
            for (int r = 0; r < 4; ++r) {
                int i = r * 256 + threadIdx.x;
                acc[r] = fma((double)a_sh[i >> 5][dl], (double)b_sh[dl][i & 31], acc[r]);
            }
        }
    }
#pragma unroll
    for (int r = 0; r < 4; ++r) {
        int i = r * 256 + threadIdx.x;
        Ntab[((size_t)(q * 8 + j) * CD + (i >> 5)) * CD + (i & 31)] = acc[r];
    }
}

// M[q][j][k][c] = sum_c' N[q][j][c][c'] * cb_j[k][c']   (fp64)
__global__ __launch_bounds__(256) void k_prep_M(const float* __restrict__ cb,
                                                const double* __restrict__ Ntab,
                                                double* __restrict__ Mt) {
    const int q = blockIdx.z, j = blockIdx.y;
    const int k = blockIdx.x * 256 + threadIdx.x;
    __shared__ double nsh[CD][CD];
    for (int i = threadIdx.x; i < CD * CD; i += 256)
        nsh[i >> 5][i & 31] = Ntab[(size_t)(q * 8 + j) * CD * CD + i];
    __syncthreads();
    double cv[CD];
    const float* cr = cb + ((size_t)j * K + k) * CD;
#pragma unroll
    for (int c = 0; c < CD; ++c) cv[c] = (double)cr[c];
    double* mo = Mt + (((size_t)(q * 8 + j) * K + k) * CD);
#pragma unroll
    for (int c = 0; c < CD; ++c) {
        double a = 0.0;
#pragma unroll
        for (int cp = 0; cp < CD; ++cp) a = fma(nsh[c][cp], cv[cp], a);
        mo[c] = a;
    }
}

// beff[q][c] = b_in[q][c] - sum_d Win_q[c][d] * (sum_{j<q} b_out[j][d])
__global__ __launch_bounds__(256) void k_prep_beff(const float* __restrict__ Win,
                                                   const float* __restrict__ b_in,
                                                   const float* __restrict__ b_out,
                                                   double* __restrict__ beff) {
    const int c = blockIdx.x, q = blockIdx.y;
    __shared__ double red[256];
    double p = 0.0;
    for (int d = threadIdx.x; d < D; d += 256) {
        double bp = 0.0;
        for (int j = 0; j < q; ++j) bp += (double)b_out[j * D + d];
        p = fma((double)Win[((size_t)q * CD + c) * D + d], bp, p);
    }
    red[threadIdx.x] = p;
    __syncthreads();
    for (int s = 128; s > 0; s >>= 1) {
        if (threadIdx.x < s) red[threadIdx.x] += red[threadIdx.x + s];
        __syncthreads();
    }
    if (threadIdx.x == 0) beff[q * CD + c] = (double)b_in[q * CD + c] - red[0];
}

// z0[q][b][c][t] = beff[q][c] + sum_d Win_q[c][d] * x[b][d][t]  (fp64)
__global__ __launch_bounds__(256) void k_gemmZ(const float* __restrict__ x,
                                               const double* __restrict__ Win64,
                                               const double* __restrict__ beff,
                                               double* __restrict__ z0) {
    int h = blockIdx.x;
    int u = h >> 3, r = h & 7;
    int q = u & 7;
    int m = r + 8 * (u >> 3);
    int b = m >> 4;
    int tc = m & 15;
    int t = tc * 256 + threadIdx.x;

    const double* w = Win64 + (size_t)q * CD * D;
    const double* be = beff + q * CD;
    const float* xb = x + (size_t)b * D * T + t;

    double acc[CD];
#pragma unroll
    for (int c = 0; c < CD; ++c) acc[c] = be[c];

    for (int d0 = 0; d0 < D; d0 += 8) {
        double xv[8];
#pragma unroll
        for (int i = 0; i < 8; ++i) xv[i] = (double)xb[(size_t)(d0 + i) * T];
#pragma unroll
        for (int c = 0; c < CD; ++c) {
            const double* wc = w + (size_t)c * D + d0;
#pragma unroll
            for (int i = 0; i < 8; ++i) acc[c] = fma(wc[i], xv[i], acc[c]);
        }
    }
    double* zo = z0 + (((size_t)q * B + b) * CD) * T + t;
#pragma unroll
    for (int c = 0; c < CD; ++c) zo[(size_t)c * T] = acc[c];
}

// ---------- fused 8-stage argmin: one launch, history in registers ----------
// Block: 256 thr = 4 waves; 64 t per block (lane=t), each wave scans a K-quarter.
// Codes streamed from global (loop-uniform addresses). fp32 prefilter with top-2
// tracking; fp64 full rescan (rounds-1..3 exact formula) when gap < 1e-4.
#define AT 64
__global__ __launch_bounds__(256) void k_argmin_fused(const double* __restrict__ z0,
                                                      const double* __restrict__ Mt,
                                                      const double* __restrict__ cbn64,
                                                      const double* __restrict__ n264,
                                                      const float* __restrict__ cbn32,
                                                      const float* __restrict__ n232,
                                                      const float* __restrict__ cb,
                                                      int* __restrict__ idxi,
                                                      float* __restrict__ idx_f,
                                                      float* __restrict__ loss) {
    const int lane = threadIdx.x & 63;
    const int kc = threadIdx.x >> 6;
    const int t = blockIdx.x * AT + lane;
    const int b = blockIdx.y;
    const size_t bt = (size_t)b * T + t;

    __shared__ float md1[4][AT], md2[4][AT];
    __shared__ int   mi1[4][AT];

    int hist[Q];   // static indexing only (q-loop fully unrolled)

#pragma unroll
    for (int q = 0; q < Q; ++q) {
        // ---- reconstruct z (fp64, fixed order) ----
        double z[CD];
#pragma unroll
        for (int c = 0; c < CD; ++c)
            z[c] = z0[(((size_t)q * B + b) * CD + c) * T + t];
#pragma unroll
        for (int j = 0; j < Q; ++j) {
            if (j < q) {
                const double* m = Mt + (((size_t)(q * 8 + j) * K + hist[j]) * CD);
#pragma unroll
                for (int c = 0; c < CD; ++c) z[c] -= m[c];
            }
        }
        double ss = 0.0;
#pragma unroll
        for (int c = 0; c < CD; ++c) ss += z[c] * z[c];
        double s = 1.0 / sqrt(ss + 1e-12);
        float znf[CD];
        float a2 = 0.0f;
#pragma unroll
        for (int c = 0; c < CD; ++c) { znf[c] = (float)(z[c] * s); a2 = fmaf(znf[c], znf[c], a2); }

        // ---- fp32 scan of this wave's K-quarter (2 codes/iter, 8 chains) ----
        float d1 = 1e30f, d2 = 1e30f; int i1 = 0;
        const float4* cq = (const float4*)(cbn32 + ((size_t)q * K + kc * 256) * CD);
        const float* nq = n232 + q * K + kc * 256;
        for (int k = 0; k < 256; k += 2) {
            const float4* c0 = cq + k * (CD / 4);
            float p0 = 0.f, p1 = 0.f, p2 = 0.f, p3 = 0.f;
            float r0 = 0.f, r1 = 0.f, r2 = 0.f, r3 = 0.f;
#pragma unroll
            for (int u = 0; u < CD / 4; ++u) {
                float4 cv = c0[u];
                float4 dv = c0[u + CD / 4];
                p0 = fmaf(znf[u * 4 + 0], cv.x, p0);
                p1 = fmaf(znf[u * 4 + 1], cv.y, p1);
                p2 = fmaf(znf[u * 4 + 2], cv.z, p2);
                p3 = fmaf(znf[u * 4 + 3], cv.w, p3);
                r0 = fmaf(znf[u * 4 + 0], dv.x, r0);
                r1 = fmaf(znf[u * 4 + 1], dv.y, r1);
                r2 = fmaf(znf[u * 4 + 2], dv.z, r2);
                r3 = fmaf(znf[u * 4 + 3], dv.w, r3);
            }
            float dist0 = fmaf(-2.0f, (p0 + p1) + (p2 + p3), a2) + nq[k];
            float dist1 = fmaf(-2.0f, (r0 + r1) + (r2 + r3), a2) + nq[k + 1];
            if (dist0 < d1) { d2 = d1; d1 = dist0; i1 = kc * 256 + k; }
            else if (dist0 < d2) { d2 = dist0; }
            if (dist1 < d1) { d2 = d1; d1 = dist1; i1 = kc * 256 + k + 1; }
            else if (dist1 < d2) { d2 = dist1; }
        }
        md1[kc][lane] = d1; md2[kc][lane] = d2; mi1[kc][lane] = i1;
        __syncthreads();

        // ---- merge (all waves redundantly -> identical hist, no broadcast) ----
        float g1 = 1e30f, g2 = 1e30f; int gi = 0;
#pragma unroll
        for (int c4 = 0; c4 < 4; ++c4) {
            float aa = md1[c4][lane], bb = md2[c4][lane]; int ii = mi1[c4][lane];
            if (aa < g1) { g2 = fminf(g1, bb); g1 = aa; gi = ii; }
            else { g2 = fminf(g2, fminf(aa, bb)); }
        }
        int bi = gi;
        if (g2 - g1 < 1e-4f) {
            // fp64 rescan: exact round-1..3 formula and order
            double zn[CD]; double A = 0.0;
#pragma unroll
            for (int c = 0; c < CD; ++c) { zn[c] = z[c] * s; A += zn[c] * zn[c]; }
            double best = 1e300; int bj = 0;
            const double* cq64 = cbn64 + (size_t)q * K * CD;
            const double* nq64 = n264 + (size_t)q * K;
            for (int k = 0; k < K; ++k) {
                double dot = 0.0;
#pragma unroll
                for (int c = 0; c < CD; ++c) dot = fma(zn[c], cq64[(size_t)k * CD + c], dot);
                double dist = (A - 2.0 * dot) + nq64[k];
                if (dist < best) { best = dist; bj = k; }
            }
            bi = bj;
        }
        hist[q] = bi;

        if (kc == 0) {
            const float* cr = cb + ((size_t)q * K + bi) * CD;
            double sq = 0.0;
#pragma unroll
            for (int c = 0; c < CD; ++c) {
                double diff = z[c] - (double)cr[c];
                sq = fma(diff, diff, sq);
            }
#pragma unroll
            for (int off = 32; off > 0; off >>= 1) sq += __shfl_down(sq, off);
            if (lane == 0)
                atomicAdd(&loss[q], (float)(sq * (1.25 / (double)((size_t)B * CD * T))));
            idxi[q * BT + bt] = bi;
            idx_f[(size_t)q * BT + bt] = (float)bi;
        }
        __syncthreads();   // md/mi reused next stage (WAR)
    }
}

// ---------- k_final as register-blocked fp32 GEMM ----------
// out_b[d][t] = sum_{j,c} Wout[j][d][c] * cb[j][idx_j[b,t]][c] + sum_j bo[j][d]
// Tile 128d x 128t, 256 thr, 8x8 per thread; K-chunk = one j (32 c's).
#define GT 128
#define GD 128
__global__ __launch_bounds__(256) void k_gemm_final(const float* __restrict__ Wout,
                                                    const float* __restrict__ bo,
                                                    const float* __restrict__ cb,
                                                    const int* __restrict__ idxi,
                                                    float* __restrict__ out) {
    const int t0 = blockIdx.x * GT;
    const int b  = blockIdx.y;
    const int d0 = blockIdx.z * GD;
    const int tx = threadIdx.x & 15;
    const int ty = threadIdx.x >> 4;
    __shared__ float Wt[CD][GD + 4];
    __shared__ float Zt[CD][GT + 4];
    __shared__ float bsum[GD];

    if (threadIdx.x < GD) {
        float sjb = 0.0f;
#pragma unroll
        for (int j = 0; j < Q; ++j) sjb += bo[j * D + d0 + threadIdx.x];
        bsum[threadIdx.x] = sjb;
    }

    float acc[8][8];
#pragma unroll
    for (int r = 0; r < 8; ++r)
#pragma unroll
        for (int cc = 0; cc < 8; ++cc) acc[r][cc] = 0.0f;

    for (int j = 0; j < Q; ++j) {
        __syncthreads();   // WAR on Wt/Zt
        for (int i = threadIdx.x; i < GD * CD; i += 256) {
            int dl = i >> 5, c = i & 31;
            Wt[c][dl] = Wout[((size_t)j * D + d0 + dl) * CD + c];
        }
        for (int i = threadIdx.x; i < GT * CD; i += 256) {
            int tl = i >> 5, c = i & 31;
            int kj = idxi[j * BT + (size_t)b * T + t0 + tl];
            Zt[c][tl] = cb[((size_t)j * K + kj) * CD + c];
        }
        __syncthreads();
#pragma unroll
        for (int k = 0; k < CD; ++k) {
            float a[8], zb[8];
            *(float4*)&a[0]  = *(const float4*)&Wt[k][ty * 8];
            *(float4*)&a[4]  = *(const float4*)&Wt[k][ty * 8 + 4];
            *(float4*)&zb[0] = *(const float4*)&Zt[k][tx * 8];
            *(float4*)&zb[4] = *(const float4*)&Zt[k][tx * 8 + 4];
#pragma unroll
            for (int r = 0; r < 8; ++r)
#pragma unroll
                for (int cc = 0; cc < 8; ++cc)
                    acc[r][cc] = fmaf(a[r], zb[cc], acc[r][cc]);
        }
    }
#pragma unroll
    for (int r = 0; r < 8; ++r) {
        const int d = d0 + ty * 8 + r;
        const float bias = bsum[ty * 8 + r];
        float4 v0, v1;
        v0.x = acc[r][0] + bias; v0.y = acc[r][1] + bias;
        v0.z = acc[r][2] + bias; v0.w = acc[r][3] + bias;
        v1.x = acc[r][4] + bias; v1.y = acc[r][5] + bias;
        v1.z = acc[r][6] + bias; v1.w = acc[r][7] + bias;
        float* op = out + ((size_t)b * D + d) * T + t0 + tx * 8;
        *(float4*)op = v0;
        *(float4*)(op + 4) = v1;
    }
}

extern "C" void kernel_launch(void* const* d_in, const int* in_sizes, int n_in,
                              void* d_out, int out_size, void* d_ws, size_t ws_size,
                              hipStream_t stream) {
    const float* x     = (const float*)d_in[0];
    const float* Win   = (const float*)d_in[1];
    const float* b_in  = (const float*)d_in[2];
    const float* Wout  = (const float*)d_in[3];
    const float* b_out = (const float*)d_in[4];
    const float* cb    = (const float*)d_in[5];

    float* out0  = (float*)d_out;
    float* idx_f = out0 + (size_t)B * D * T;
    float* loss  = idx_f + (size_t)Q * BT;

    char* sc = (char*)d_out;   // scratch: dead before k_gemm_final writes out0
    double* z0    = (double*)(sc + OFF_Z0);
    double* Mt    = (double*)(sc + OFF_MT);
    double* cbn64 = (double*)(sc + OFF_CBN);
    double* n264  = (double*)(sc + OFF_N264);
    double* Ntab  = (double*)(sc + OFF_NT);
    double* beff  = (double*)(sc + OFF_BEFF);
    float*  cbn32 = (float*)(sc + OFF_C32);
    float*  n232  = (float*)(sc + OFF_N232);
    double* Win64 = (double*)(sc + OFF_W64);
    int*    idxi  = (int*)d_ws;                  // 1 MB, safe for gemm_final

    k_zero_losses<<<1, 64, 0, stream>>>(loss);
    k_norm<<<(Q * K) / 256, 256, 0, stream>>>(cb, cbn64, n264, cbn32, n232);
    k_cvtW<<<(Q * CD * D) / 256, 256, 0, stream>>>(Win, Win64);
    k_prep_N<<<64, 256, 0, stream>>>(Win, Wout, Ntab);
    k_prep_M<<<dim3(K / 256, 8, 8), 256, 0, stream>>>(cb, Ntab, Mt);
    k_prep_beff<<<dim3(CD, Q), 256, 0, stream>>>(Win, b_in, b_out, beff);

    k_gemmZ<<<Q * B * (T / 256), 256, 0, stream>>>(x, Win64, beff, z0);

    k_argmin_fused<<<dim3(T / AT, B), 256, 0, stream>>>(z0, Mt, cbn64, n264,
                                                        cbn32, n232, cb,
                                                        idxi, idx_f, loss);

    k_gemm_final<<<dim3(T / GT, B, D / GD), 256, 0, stream>>>(Wout, b_out, cb, idxi, out0);
}

// Round 5
// 2499.576 us; speedup vs baseline: 2.2197x; 1.5025x over previous
//
#include <hip/hip_runtime.h>
#include <math.h>

#define B 8
#define D 1024
#define T 4096
#define Q 8
#define K 1024
#define CD 32
#define BT (B * T)

// ---------------- scratch layout inside d_out (bytes) ----------------
// d_out floats [0 .. B*D*T) are scratch until k_gemm_final (last kernel) writes them.
// k_gemm_final reads ONLY inputs + idxi (in d_ws) -> no overlap hazard.
#define OFF_Z0   ((size_t)0)                            // f64 [Q][B][CD][T]  64 MB
#define OFF_MT   (OFF_Z0 + (size_t)Q * B * CD * T * 8)  // f64 [8][8][K][CD]  16 MB
#define OFF_CBN  (OFF_MT + (size_t)64 * K * CD * 8)     // f64 [Q][K][CD]      2 MB
#define OFF_N264 (OFF_CBN + (size_t)Q * K * CD * 8)     // f64 [Q][K]         64 KB
#define OFF_NT   (OFF_N264 + (size_t)Q * K * 8)         // f64 [64][CD][CD]  512 KB
#define OFF_BEFF (OFF_NT + (size_t)64 * CD * CD * 8)    // f64 [Q][CD]         2 KB
#define OFF_C32  (OFF_BEFF + (size_t)Q * CD * 8)        // f32 [Q][K][CD]      1 MB
#define OFF_N232 (OFF_C32 + (size_t)Q * K * CD * 4)     // f32 [Q][K]         32 KB
#define OFF_W64  (OFF_N232 + (size_t)Q * K * 4)         // f64 [Q][CD][D]      2 MB
// idxi i32 [Q][BT] lives in d_ws @ 0 (1 MB)

__global__ void k_zero_losses(float* __restrict__ loss) {
    if (threadIdx.x < Q) loss[threadIdx.x] = 0.0f;
}

// Normalize codebooks fp64 + fp32 copies for the prefilter.
__global__ __launch_bounds__(256) void k_norm(const float* __restrict__ cb,
                                              double* __restrict__ cbn64,
                                              double* __restrict__ n264,
                                              float* __restrict__ cbn32,
                                              float* __restrict__ n232) {
    int i = blockIdx.x * 256 + threadIdx.x;   // 0..Q*K-1
    const float* c = cb + (size_t)i * CD;
    double v[CD];
    double ss = 0.0;
#pragma unroll
    for (int j = 0; j < CD; ++j) { v[j] = (double)c[j]; ss += v[j] * v[j]; }
    double s = 1.0 / sqrt(ss + 1e-12);
    double n2 = 0.0;
    double* o = cbn64 + (size_t)i * CD;
    float* o32 = cbn32 + (size_t)i * CD;
#pragma unroll
    for (int j = 0; j < CD; ++j) {
        double vn = v[j] * s;
        o[j] = vn; o32[j] = (float)vn; n2 += vn * vn;
    }
    n264[i] = n2; n232[i] = (float)n2;
}

// Win -> fp64 copy
__global__ __launch_bounds__(256) void k_cvtW(const float* __restrict__ Win,
                                              double* __restrict__ Win64) {
    int i = blockIdx.x * 256 + threadIdx.x;
    Win64[i] = (double)Win[i];
}

// N[q][j][c][c'] = sum_d Win_q[c,d] * Wout_j[d,c']   (fp64)
__global__ __launch_bounds__(256) void k_prep_N(const float* __restrict__ Win,
                                                const float* __restrict__ Wout,
                                                double* __restrict__ Ntab) {
    const int q = blockIdx.x >> 3, j = blockIdx.x & 7;
    __shared__ float a_sh[CD][128];
    __shared__ float b_sh[128][CD];
    double acc[4] = {0.0, 0.0, 0.0, 0.0};
    for (int d0 = 0; d0 < D; d0 += 128) {
        __syncthreads();
        for (int i = threadIdx.x; i < CD * 128; i += 256) {
            int cc = i >> 7, dl = i & 127;
            a_sh[cc][dl] = Win[((size_t)q * CD + cc) * D + d0 + dl];
        }
        for (int i = threadIdx.x; i < 128 * CD; i += 256) {
            int dl = i >> 5, cc = i & 31;
            b_sh[dl][cc] = Wout[((size_t)j * D + d0 + dl) * CD + cc];
        }
        __syncthreads();
        for (int dl = 0; dl < 128; ++dl) {
#pragma unroll
            for (int r = 0; r < 4; ++r) {
                int i = r * 256 + threadIdx.x;
                acc[r] = fma((double)a_sh[i >> 5][dl], (double)b_sh[dl][i & 31], acc[r]);
            }
        }
    }
#pragma unroll
    for (int r = 0; r < 4; ++r) {
        int i = r * 256 + threadIdx.x;
        Ntab[((size_t)(q * 8 + j) * CD + (i >> 5)) * CD + (i & 31)] = acc[r];
    }
}

// M[q][j][k][c] = sum_c' N[q][j][c][c'] * cb_j[k][c']   (fp64)
__global__ __launch_bounds__(256) void k_prep_M(const float* __restrict__ cb,
                                                const double* __restrict__ Ntab,
                                                double* __restrict__ Mt) {
    const int q = blockIdx.z, j = blockIdx.y;
    const int k = blockIdx.x * 256 + threadIdx.x;
    __shared__ double nsh[CD][CD];
    for (int i = threadIdx.x; i < CD * CD; i += 256)
        nsh[i >> 5][i & 31] = Ntab[(size_t)(q * 8 + j) * CD * CD + i];
    __syncthreads();
    double cv[CD];
    const float* cr = cb + ((size_t)j * K + k) * CD;
#pragma unroll
    for (int c = 0; c < CD; ++c) cv[c] = (double)cr[c];
    double* mo = Mt + (((size_t)(q * 8 + j) * K + k) * CD);
#pragma unroll
    for (int c = 0; c < CD; ++c) {
        double a = 0.0;
#pragma unroll
        for (int cp = 0; cp < CD; ++cp) a = fma(nsh[c][cp], cv[cp], a);
        mo[c] = a;
    }
}

// beff[q][c] = b_in[q][c] - sum_d Win_q[c][d] * (sum_{j<q} b_out[j][d])
__global__ __launch_bounds__(256) void k_prep_beff(const float* __restrict__ Win,
                                                   const float* __restrict__ b_in,
                                                   const float* __restrict__ b_out,
                                                   double* __restrict__ beff) {
    const int c = blockIdx.x, q = blockIdx.y;
    __shared__ double red[256];
    double p = 0.0;
    for (int d = threadIdx.x; d < D; d += 256) {
        double bp = 0.0;
        for (int j = 0; j < q; ++j) bp += (double)b_out[j * D + d];
        p = fma((double)Win[((size_t)q * CD + c) * D + d], bp, p);
    }
    red[threadIdx.x] = p;
    __syncthreads();
    for (int s = 128; s > 0; s >>= 1) {
        if (threadIdx.x < s) red[threadIdx.x] += red[threadIdx.x + s];
        __syncthreads();
    }
    if (threadIdx.x == 0) beff[q * CD + c] = (double)b_in[q * CD + c] - red[0];
}

// z0[q][b][c][t] = beff[q][c] + sum_d Win_q[c][d] * x[b][d][t]  (fp64)
__global__ __launch_bounds__(256) void k_gemmZ(const float* __restrict__ x,
                                               const double* __restrict__ Win64,
                                               const double* __restrict__ beff,
                                               double* __restrict__ z0) {
    int h = blockIdx.x;
    int u = h >> 3, r = h & 7;
    int q = u & 7;
    int m = r + 8 * (u >> 3);
    int b = m >> 4;
    int tc = m & 15;
    int t = tc * 256 + threadIdx.x;

    const double* w = Win64 + (size_t)q * CD * D;
    const double* be = beff + q * CD;
    const float* xb = x + (size_t)b * D * T + t;

    double acc[CD];
#pragma unroll
    for (int c = 0; c < CD; ++c) acc[c] = be[c];

    for (int d0 = 0; d0 < D; d0 += 8) {
        double xv[8];
#pragma unroll
        for (int i = 0; i < 8; ++i) xv[i] = (double)xb[(size_t)(d0 + i) * T];
#pragma unroll
        for (int c = 0; c < CD; ++c) {
            const double* wc = w + (size_t)c * D + d0;
#pragma unroll
            for (int i = 0; i < 8; ++i) acc[c] = fma(wc[i], xv[i], acc[c]);
        }
    }
    double* zo = z0 + (((size_t)q * B + b) * CD) * T + t;
#pragma unroll
    for (int c = 0; c < CD; ++c) zo[(size_t)c * T] = acc[c];
}

// insert (dd,ii) into sorted top-4 (d1<=d2<=d3<=d4)
#define INS4(dd, ii)                                                           \
    do {                                                                       \
        float _d = (dd); int _i = (ii);                                        \
        if (_d < d4) {                                                         \
            d4 = _d; i4 = _i;                                                  \
            if (d4 < d3) { float tf = d3; d3 = d4; d4 = tf; int ti = i3; i3 = i4; i4 = ti; } \
            if (d3 < d2) { float tf = d2; d2 = d3; d3 = tf; int ti = i2; i2 = i3; i3 = ti; } \
            if (d2 < d1) { float tf = d1; d1 = d2; d2 = tf; int ti = i1; i1 = i2; i2 = ti; } \
        }                                                                      \
    } while (0)

// ---------- fused 8-stage argmin ----------
// Block: 256 thr = 4 waves; 64 t (lane = t), wave kc scans K-quarter kc.
// fp32 top-4 prefilter fed by SCALAR loads (uniform addresses); fp64 eval of the
// 4 merged candidates (exact round-1 chain order); full fp64 rescan only when
// d4-d1 < 1e-4 (rare: needs 4 codes within the window).
#define AT 64
__global__ __launch_bounds__(256) void k_argmin_fused(const double* __restrict__ z0,
                                                      const double* __restrict__ Mt,
                                                      const double* __restrict__ cbn64,
                                                      const double* __restrict__ n264,
                                                      const float* __restrict__ cbn32,
                                                      const float* __restrict__ n232,
                                                      const float* __restrict__ cb,
                                                      int* __restrict__ idxi,
                                                      float* __restrict__ idx_f,
                                                      float* __restrict__ loss) {
    const int lane = threadIdx.x & 63;
    const int kc_v = threadIdx.x >> 6;
    const int kc = __builtin_amdgcn_readfirstlane(kc_v);   // provably uniform
    const int t = blockIdx.x * AT + lane;
    const int b = blockIdx.y;
    const size_t bt = (size_t)b * T + t;

    __shared__ float sd[4][4][AT];
    __shared__ int   si[4][4][AT];

    int hist[Q];   // static indexing only (q-loop fully unrolled)

#pragma unroll
    for (int q = 0; q < Q; ++q) {
        // ---- reconstruct z (fp64, fixed order), then normalize in place ----
        double zn[CD];
#pragma unroll
        for (int c = 0; c < CD; ++c)
            zn[c] = z0[(((size_t)q * B + b) * CD + c) * T + t];
#pragma unroll
        for (int j = 0; j < Q; ++j) {
            if (j < q) {
                const double* m = Mt + (((size_t)(q * 8 + j) * K + hist[j]) * CD);
#pragma unroll
                for (int c = 0; c < CD; ++c) zn[c] -= m[c];
            }
        }
        double ss = 0.0;
#pragma unroll
        for (int c = 0; c < CD; ++c) ss += zn[c] * zn[c];
        double rnorm = sqrt(ss + 1e-12);
        double s = 1.0 / rnorm;
        double A = 0.0;
        float znf[CD];
        float a2 = 0.0f;
#pragma unroll
        for (int c = 0; c < CD; ++c) {
            zn[c] = zn[c] * s;                 // zn now holds normalized z (fp64)
            A += zn[c] * zn[c];                // exact round-1 order
            znf[c] = (float)zn[c];
            a2 = fmaf(znf[c], znf[c], a2);
        }

        // ---- fp32 top-4 scan of this wave's K-quarter (scalar-fed) ----
        float d1 = 1e30f, d2 = 1e30f, d3 = 1e30f, d4 = 1e30f;
        int i1 = 0, i2 = 0, i3 = 0, i4 = 0;
        {
            const float4* cp = (const float4*)(cbn32 + ((size_t)q * K + (size_t)kc * 256) * CD);
            const float* nq = n232 + q * K + kc * 256;
            for (int k = 0; k < 256; k += 2) {
                const float4* c0 = cp + k * (CD / 4);
                float p0 = 0.f, p1 = 0.f, p2 = 0.f, p3 = 0.f;
                float r0 = 0.f, r1 = 0.f, r2 = 0.f, r3 = 0.f;
#pragma unroll
                for (int u = 0; u < CD / 4; ++u) {
                    float4 cv = c0[u];
                    float4 dv = c0[u + CD / 4];
                    p0 = fmaf(znf[u * 4 + 0], cv.x, p0);
                    p1 = fmaf(znf[u * 4 + 1], cv.y, p1);
                    p2 = fmaf(znf[u * 4 + 2], cv.z, p2);
                    p3 = fmaf(znf[u * 4 + 3], cv.w, p3);
                    r0 = fmaf(znf[u * 4 + 0], dv.x, r0);
                    r1 = fmaf(znf[u * 4 + 1], dv.y, r1);
                    r2 = fmaf(znf[u * 4 + 2], dv.z, r2);
                    r3 = fmaf(znf[u * 4 + 3], dv.w, r3);
                }
                float dist0 = fmaf(-2.0f, (p0 + p1) + (p2 + p3), a2) + nq[k];
                float dist1 = fmaf(-2.0f, (r0 + r1) + (r2 + r3), a2) + nq[k + 1];
                INS4(dist0, kc * 256 + k);
                INS4(dist1, kc * 256 + k + 1);
            }
        }
        sd[kc_v][0][lane] = d1; sd[kc_v][1][lane] = d2;
        sd[kc_v][2][lane] = d3; sd[kc_v][3][lane] = d4;
        si[kc_v][0][lane] = i1; si[kc_v][1][lane] = i2;
        si[kc_v][2][lane] = i3; si[kc_v][3][lane] = i4;
        __syncthreads();

        // ---- merge 16 -> global top-4 (all threads redundantly -> same hist) ----
        {
            d1 = d2 = d3 = d4 = 1e30f; i1 = i2 = i3 = i4 = 0;
#pragma unroll
            for (int w = 0; w < 4; ++w)
#pragma unroll
                for (int s4 = 0; s4 < 4; ++s4)
                    INS4(sd[w][s4][lane], si[w][s4][lane]);
        }

        int bi;
        if (d4 - d1 >= 1e-4f) {
            // winner provably among {i1..i4}; evaluate in fp64, index-ascending
            int j1 = i1, j2 = i2, j3 = i3, j4 = i4;
            { int tt; if (j1 > j2) { tt = j1; j1 = j2; j2 = tt; }
                      if (j3 > j4) { tt = j3; j3 = j4; j4 = tt; }
                      if (j1 > j3) { tt = j1; j1 = j3; j3 = tt; }
                      if (j2 > j4) { tt = j2; j2 = j4; j4 = tt; }
                      if (j2 > j3) { tt = j2; j2 = j3; j3 = tt; } }
            const double* cq64 = cbn64 + (size_t)q * K * CD;
            const double* nq64 = n264 + (size_t)q * K;
            double dot1v = 0.0, dot2v = 0.0, dot3v = 0.0, dot4v = 0.0;
            const double* r1p = cq64 + (size_t)j1 * CD;
            const double* r2p = cq64 + (size_t)j2 * CD;
            const double* r3p = cq64 + (size_t)j3 * CD;
            const double* r4p = cq64 + (size_t)j4 * CD;
#pragma unroll
            for (int c = 0; c < CD; ++c) {
                dot1v = fma(zn[c], r1p[c], dot1v);
                dot2v = fma(zn[c], r2p[c], dot2v);
                dot3v = fma(zn[c], r3p[c], dot3v);
                dot4v = fma(zn[c], r4p[c], dot4v);
            }
            double e1 = (A - 2.0 * dot1v) + nq64[j1];
            double e2 = (A - 2.0 * dot2v) + nq64[j2];
            double e3 = (A - 2.0 * dot3v) + nq64[j3];
            double e4 = (A - 2.0 * dot4v) + nq64[j4];
            double best = e1; bi = j1;
            if (e2 < best) { best = e2; bi = j2; }
            if (e3 < best) { best = e3; bi = j3; }
            if (e4 < best) { best = e4; bi = j4; }
        } else {
            // rare full fp64 rescan (exact round-1 formula; 2-code ILP)
            double best = 1e300; bi = 0;
            const double* cq64 = cbn64 + (size_t)q * K * CD;
            const double* nq64 = n264 + (size_t)q * K;
            for (int k = 0; k < K; k += 2) {
                double dot0 = 0.0, dot1 = 0.0;
                const double* c0 = cq64 + (size_t)k * CD;
                const double* c1 = c0 + CD;
#pragma unroll
                for (int c = 0; c < CD; ++c) {
                    dot0 = fma(zn[c], c0[c], dot0);
                    dot1 = fma(zn[c], c1[c], dot1);
                }
                double dist0 = (A - 2.0 * dot0) + nq64[k];
                double dist1 = (A - 2.0 * dot1) + nq64[k + 1];
                if (dist0 < best) { best = dist0; bi = k; }
                if (dist1 < best) { best = dist1; bi = k + 1; }
            }
        }
        hist[q] = bi;

        if (kc_v == 0) {
            const float* cr = cb + ((size_t)q * K + bi) * CD;
            double sq = 0.0;
#pragma unroll
            for (int c = 0; c < CD; ++c) {
                double diff = zn[c] * rnorm - (double)cr[c];   // round-1 loss form
                sq = fma(diff, diff, sq);
            }
#pragma unroll
            for (int off = 32; off > 0; off >>= 1) sq += __shfl_down(sq, off);
            if (lane == 0)
                atomicAdd(&loss[q], (float)(sq * (1.25 / (double)((size_t)B * CD * T))));
            idxi[q * BT + bt] = bi;
            idx_f[(size_t)q * BT + bt] = (float)bi;
        }
        __syncthreads();   // sd/si reused next stage (WAR)
    }
}

// ---------- k_final as register-blocked fp32 GEMM ----------
#define GT 128
#define GD 128
__global__ __launch_bounds__(256) void k_gemm_final(const float* __restrict__ Wout,
                                                    const float* __restrict__ bo,
                                                    const float* __restrict__ cb,
                                                    const int* __restrict__ idxi,
                                                    float* __restrict__ out) {
    const int t0 = blockIdx.x * GT;
    const int b  = blockIdx.y;
    const int d0 = blockIdx.z * GD;
    const int tx = threadIdx.x & 15;
    const int ty = threadIdx.x >> 4;
    __shared__ float Wt[CD][GD + 4];
    __shared__ float Zt[CD][GT + 4];
    __shared__ float bsum[GD];

    if (threadIdx.x < GD) {
        float sjb = 0.0f;
#pragma unroll
        for (int j = 0; j < Q; ++j) sjb += bo[j * D + d0 + threadIdx.x];
        bsum[threadIdx.x] = sjb;
    }

    float acc[8][8];
#pragma unroll
    for (int r = 0; r < 8; ++r)
#pragma unroll
        for (int cc = 0; cc < 8; ++cc) acc[r][cc] = 0.0f;

    for (int j = 0; j < Q; ++j) {
        __syncthreads();   // WAR on Wt/Zt
        for (int i = threadIdx.x; i < GD * CD; i += 256) {
            int dl = i >> 5, c = i & 31;
            Wt[c][dl] = Wout[((size_t)j * D + d0 + dl) * CD + c];
        }
        for (int i = threadIdx.x; i < GT * CD; i += 256) {
            int tl = i >> 5, c = i & 31;
            int kj = idxi[j * BT + (size_t)b * T + t0 + tl];
            Zt[c][tl] = cb[((size_t)j * K + kj) * CD + c];
        }
        __syncthreads();
#pragma unroll
        for (int k = 0; k < CD; ++k) {
            float a[8], zb[8];
            *(float4*)&a[0]  = *(const float4*)&Wt[k][ty * 8];
            *(float4*)&a[4]  = *(const float4*)&Wt[k][ty * 8 + 4];
            *(float4*)&zb[0] = *(const float4*)&Zt[k][tx * 8];
            *(float4*)&zb[4] = *(const float4*)&Zt[k][tx * 8 + 4];
#pragma unroll
            for (int r = 0; r < 8; ++r)
#pragma unroll
                for (int cc = 0; cc < 8; ++cc)
                    acc[r][cc] = fmaf(a[r], zb[cc], acc[r][cc]);
        }
    }
#pragma unroll
    for (int r = 0; r < 8; ++r) {
        const int d = d0 + ty * 8 + r;
        const float bias = bsum[ty * 8 + r];
        float4 v0, v1;
        v0.x = acc[r][0] + bias; v0.y = acc[r][1] + bias;
        v0.z = acc[r][2] + bias; v0.w = acc[r][3] + bias;
        v1.x = acc[r][4] + bias; v1.y = acc[r][5] + bias;
        v1.z = acc[r][6] + bias; v1.w = acc[r][7] + bias;
        float* op = out + ((size_t)b * D + d) * T + t0 + tx * 8;
        *(float4*)op = v0;
        *(float4*)(op + 4) = v1;
    }
}

extern "C" void kernel_launch(void* const* d_in, const int* in_sizes, int n_in,
                              void* d_out, int out_size, void* d_ws, size_t ws_size,
                              hipStream_t stream) {
    const float* x     = (const float*)d_in[0];
    const float* Win   = (const float*)d_in[1];
    const float* b_in  = (const float*)d_in[2];
    const float* Wout  = (const float*)d_in[3];
    const float* b_out = (const float*)d_in[4];
    const float* cb    = (const float*)d_in[5];

    float* out0  = (float*)d_out;
    float* idx_f = out0 + (size_t)B * D * T;
    float* loss  = idx_f + (size_t)Q * BT;

    char* sc = (char*)d_out;   // scratch: dead before k_gemm_final writes out0
    double* z0    = (double*)(sc + OFF_Z0);
    double* Mt    = (double*)(sc + OFF_MT);
    double* cbn64 = (double*)(sc + OFF_CBN);
    double* n264  = (double*)(sc + OFF_N264);
    double* Ntab  = (double*)(sc + OFF_NT);
    double* beff  = (double*)(sc + OFF_BEFF);
    float*  cbn32 = (float*)(sc + OFF_C32);
    float*  n232  = (float*)(sc + OFF_N232);
    double* Win64 = (double*)(sc + OFF_W64);
    int*    idxi  = (int*)d_ws;                  // 1 MB, safe for gemm_final

    k_zero_losses<<<1, 64, 0, stream>>>(loss);
    k_norm<<<(Q * K) / 256, 256, 0, stream>>>(cb, cbn64, n264, cbn32, n232);
    k_cvtW<<<(Q * CD * D) / 256, 256, 0, stream>>>(Win, Win64);
    k_prep_N<<<64, 256, 0, stream>>>(Win, Wout, Ntab);
    k_prep_M<<<dim3(K / 256, 8, 8), 256, 0, stream>>>(cb, Ntab, Mt);
    k_prep_beff<<<dim3(CD, Q), 256, 0, stream>>>(Win, b_in, b_out, beff);

    k_gemmZ<<<Q * B * (T / 256), 256, 0, stream>>>(x, Win64, beff, z0);

    k_argmin_fused<<<dim3(T / AT, B), 256, 0, stream>>>(z0, Mt, cbn64, n264,
                                                        cbn32, n232, cb,
                                                        idxi, idx_f, loss);

    k_gemm_final<<<dim3(T / GT, B, D / GD), 256, 0, stream>>>(Wout, b_out, cb, idxi, out0);
}

// Round 6
// 2223.405 us; speedup vs baseline: 2.4954x; 1.1242x over previous
//
#include <hip/hip_runtime.h>
#include <math.h>

#define B 8
#define D 1024
#define T 4096
#define Q 8
#define K 1024
#define CD 32
#define BT (B * T)

// ---------------- scratch layout inside d_out (bytes) ----------------
// d_out floats [0 .. B*D*T) are scratch until k_gemm_final (last kernel) writes them.
// k_gemm_final reads ONLY inputs + idxi (in d_ws) -> no overlap hazard.
#define OFF_Z0   ((size_t)0)                            // f64 [Q][B][CD][T]  64 MB
#define OFF_MT   (OFF_Z0 + (size_t)Q * B * CD * T * 8)  // f64 [8][8][K][CD]  16 MB
#define OFF_CBN  (OFF_MT + (size_t)64 * K * CD * 8)     // f64 [Q][K][CD]      2 MB
#define OFF_N264 (OFF_CBN + (size_t)Q * K * CD * 8)     // f64 [Q][K]         64 KB
#define OFF_NT   (OFF_N264 + (size_t)Q * K * 8)         // f64 [64][CD][CD]  512 KB
#define OFF_BEFF (OFF_NT + (size_t)64 * CD * CD * 8)    // f64 [Q][CD]         2 KB
#define OFF_C32  (OFF_BEFF + (size_t)Q * CD * 8)        // f32 [Q][K][CD]      1 MB
#define OFF_N232 (OFF_C32 + (size_t)Q * K * CD * 4)     // f32 [Q][K]         32 KB
#define OFF_W64  (OFF_N232 + (size_t)Q * K * 4)         // f64 [Q][CD][D]      2 MB
// idxi i32 [Q][BT] lives in d_ws @ 0 (1 MB)

__global__ void k_zero_losses(float* __restrict__ loss) {
    if (threadIdx.x < Q) loss[threadIdx.x] = 0.0f;
}

// Normalize codebooks fp64 + fp32 copies for the prefilter.
__global__ __launch_bounds__(256) void k_norm(const float* __restrict__ cb,
                                              double* __restrict__ cbn64,
                                              double* __restrict__ n264,
                                              float* __restrict__ cbn32,
                                              float* __restrict__ n232) {
    int i = blockIdx.x * 256 + threadIdx.x;   // 0..Q*K-1
    const float* c = cb + (size_t)i * CD;
    double v[CD];
    double ss = 0.0;
#pragma unroll
    for (int j = 0; j < CD; ++j) { v[j] = (double)c[j]; ss += v[j] * v[j]; }
    double s = 1.0 / sqrt(ss + 1e-12);
    double n2 = 0.0;
    double* o = cbn64 + (size_t)i * CD;
    float* o32 = cbn32 + (size_t)i * CD;
#pragma unroll
    for (int j = 0; j < CD; ++j) {
        double vn = v[j] * s;
        o[j] = vn; o32[j] = (float)vn; n2 += vn * vn;
    }
    n264[i] = n2; n232[i] = (float)n2;
}

// Win -> fp64 copy
__global__ __launch_bounds__(256) void k_cvtW(const float* __restrict__ Win,
                                              double* __restrict__ Win64) {
    int i = blockIdx.x * 256 + threadIdx.x;
    Win64[i] = (double)Win[i];
}

// N[q][j][c][c'] = sum_d Win_q[c,d] * Wout_j[d,c']   (fp64)
__global__ __launch_bounds__(256) void k_prep_N(const float* __restrict__ Win,
                                                const float* __restrict__ Wout,
                                                double* __restrict__ Ntab) {
    const int q = blockIdx.x >> 3, j = blockIdx.x & 7;
    __shared__ float a_sh[CD][128];
    __shared__ float b_sh[128][CD];
    double acc[4] = {0.0, 0.0, 0.0, 0.0};
    for (int d0 = 0; d0 < D; d0 += 128) {
        __syncthreads();
        for (int i = threadIdx.x; i < CD * 128; i += 256) {
            int cc = i >> 7, dl = i & 127;
            a_sh[cc][dl] = Win[((size_t)q * CD + cc) * D + d0 + dl];
        }
        for (int i = threadIdx.x; i < 128 * CD; i += 256) {
            int dl = i >> 5, cc = i & 31;
            b_sh[dl][cc] = Wout[((size_t)j * D + d0 + dl) * CD + cc];
        }
        __syncthreads();
        for (int dl = 0; dl < 128; ++dl) {
#pragma unroll
            for (int r = 0; r < 4; ++r) {
                int i = r * 256 + threadIdx.x;
                acc[r] = fma((double)a_sh[i >> 5][dl], (double)b_sh[dl][i & 31], acc[r]);
            }
        }
    }
#pragma unroll
    for (int r = 0; r < 4; ++r) {
        int i = r * 256 + threadIdx.x;
        Ntab[((size_t)(q * 8 + j) * CD + (i >> 5)) * CD + (i & 31)] = acc[r];
    }
}

// M[q][j][k][c] = sum_c' N[q][j][c][c'] * cb_j[k][c']   (fp64)
__global__ __launch_bounds__(256) void k_prep_M(const float* __restrict__ cb,
                                                const double* __restrict__ Ntab,
                                                double* __restrict__ Mt) {
    const int q = blockIdx.z, j = blockIdx.y;
    const int k = blockIdx.x * 256 + threadIdx.x;
    __shared__ double nsh[CD][CD];
    for (int i = threadIdx.x; i < CD * CD; i += 256)
        nsh[i >> 5][i & 31] = Ntab[(size_t)(q * 8 + j) * CD * CD + i];
    __syncthreads();
    double cv[CD];
    const float* cr = cb + ((size_t)j * K + k) * CD;
#pragma unroll
    for (int c = 0; c < CD; ++c) cv[c] = (double)cr[c];
    double* mo = Mt + (((size_t)(q * 8 + j) * K + k) * CD);
#pragma unroll
    for (int c = 0; c < CD; ++c) {
        double a = 0.0;
#pragma unroll
        for (int cp = 0; cp < CD; ++cp) a = fma(nsh[c][cp], cv[cp], a);
        mo[c] = a;
    }
}

// beff[q][c] = b_in[q][c] - sum_d Win_q[c][d] * (sum_{j<q} b_out[j][d])
__global__ __launch_bounds__(256) void k_prep_beff(const float* __restrict__ Win,
                                                   const float* __restrict__ b_in,
                                                   const float* __restrict__ b_out,
                                                   double* __restrict__ beff) {
    const int c = blockIdx.x, q = blockIdx.y;
    __shared__ double red[256];
    double p = 0.0;
    for (int d = threadIdx.x; d < D; d += 256) {
        double bp = 0.0;
        for (int j = 0; j < q; ++j) bp += (double)b_out[j * D + d];
        p = fma((double)Win[((size_t)q * CD + c) * D + d], bp, p);
    }
    red[threadIdx.x] = p;
    __syncthreads();
    for (int s = 128; s > 0; s >>= 1) {
        if (threadIdx.x < s) red[threadIdx.x] += red[threadIdx.x + s];
        __syncthreads();
    }
    if (threadIdx.x == 0) beff[q * CD + c] = (double)b_in[q * CD + c] - red[0];
}

// z0[q][b][c][t] = beff[q][c] + sum_d Win_q[c][d] * x[b][d][t]  (fp64)
__global__ __launch_bounds__(256) void k_gemmZ(const float* __restrict__ x,
                                               const double* __restrict__ Win64,
                                               const double* __restrict__ beff,
                                               double* __restrict__ z0) {
    int h = blockIdx.x;
    int u = h >> 3, r = h & 7;
    int q = u & 7;
    int m = r + 8 * (u >> 3);
    int b = m >> 4;
    int tc = m & 15;
    int t = tc * 256 + threadIdx.x;

    const double* w = Win64 + (size_t)q * CD * D;
    const double* be = beff + q * CD;
    const float* xb = x + (size_t)b * D * T + t;

    double acc[CD];
#pragma unroll
    for (int c = 0; c < CD; ++c) acc[c] = be[c];

    for (int d0 = 0; d0 < D; d0 += 8) {
        double xv[8];
#pragma unroll
        for (int i = 0; i < 8; ++i) xv[i] = (double)xb[(size_t)(d0 + i) * T];
#pragma unroll
        for (int c = 0; c < CD; ++c) {
            const double* wc = w + (size_t)c * D + d0;
#pragma unroll
            for (int i = 0; i < 8; ++i) acc[c] = fma(wc[i], xv[i], acc[c]);
        }
    }
    double* zo = z0 + (((size_t)q * B + b) * CD) * T + t;
#pragma unroll
    for (int c = 0; c < CD; ++c) zo[(size_t)c * T] = acc[c];
}

// insert (dd,ii) into sorted top-4 (d1<=d2<=d3<=d4)
#define INS4(dd, ii)                                                           \
    do {                                                                       \
        float _d = (dd); int _i = (ii);                                        \
        if (_d < d4) {                                                         \
            d4 = _d; i4 = _i;                                                  \
            if (d4 < d3) { float tf = d3; d3 = d4; d4 = tf; int ti = i3; i3 = i4; i4 = ti; } \
            if (d3 < d2) { float tf = d2; d2 = d3; d3 = tf; int ti = i2; i2 = i3; i3 = ti; } \
            if (d2 < d1) { float tf = d1; d1 = d2; d2 = tf; int ti = i1; i1 = i2; i2 = ti; } \
        }                                                                      \
    } while (0)

// ---------- fused 8-stage argmin, wave-specialized ----------
// 256 thr = 4 waves, 64 t per block (lane = t).
// Wave 0: all fp64 (reconstruct/normalize -> publish znf,a2 to LDS; merge;
//         candidate eval; rare rescan; loss; index writes). History in regs.
// Waves 0-3: fp32 top-4 scan of their K-quarter, 4 codes/iter for ILP.
#define AT 64
__global__ __launch_bounds__(256) void k_argmin_fused(const double* __restrict__ z0,
                                                      const double* __restrict__ Mt,
                                                      const double* __restrict__ cbn64,
                                                      const double* __restrict__ n264,
                                                      const float* __restrict__ cbn32,
                                                      const float* __restrict__ n232,
                                                      const float* __restrict__ cb,
                                                      int* __restrict__ idxi,
                                                      float* __restrict__ idx_f,
                                                      float* __restrict__ loss) {
    const int lane = threadIdx.x & 63;
    const int kc_v = threadIdx.x >> 6;
    const int kc = __builtin_amdgcn_readfirstlane(kc_v);   // uniform wave id
    const int t = blockIdx.x * AT + lane;
    const int b = blockIdx.y;
    const size_t bt = (size_t)b * T + t;

    __shared__ float znf_s[CD][AT];    // [c][lane] -> 2-way bank alias (free)
    __shared__ float a2_s[AT];
    __shared__ float sd[4][4][AT];
    __shared__ int   si[4][4][AT];

    int hist[Q];        // only wave 0 reads/writes meaningfully
    double zn[CD];      // live only inside wave-0 branches
    double rnorm = 0.0, A = 0.0;

#pragma unroll
    for (int q = 0; q < Q; ++q) {
        // ---- wave 0: reconstruct z (fp64, exact round-1..5 order), publish znf ----
        if (kc_v == 0) {
#pragma unroll
            for (int c = 0; c < CD; ++c)
                zn[c] = z0[(((size_t)q * B + b) * CD + c) * T + t];
#pragma unroll
            for (int j = 0; j < Q; ++j) {
                if (j < q) {
                    const double* m = Mt + (((size_t)(q * 8 + j) * K + hist[j]) * CD);
#pragma unroll
                    for (int c = 0; c < CD; ++c) zn[c] -= m[c];
                }
            }
            double ss = 0.0;
#pragma unroll
            for (int c = 0; c < CD; ++c) ss += zn[c] * zn[c];
            rnorm = sqrt(ss + 1e-12);
            double s = 1.0 / rnorm;
            A = 0.0;
            float a2 = 0.0f;
#pragma unroll
            for (int c = 0; c < CD; ++c) {
                zn[c] = zn[c] * s;
                A += zn[c] * zn[c];
                float zf = (float)zn[c];
                znf_s[c][lane] = zf;
                a2 = fmaf(zf, zf, a2);
            }
            a2_s[lane] = a2;
        }
        __syncthreads();

        // ---- all waves: fp32 top-4 scan of own K-quarter, 4 codes/iter ----
        float znf[CD];
#pragma unroll
        for (int c = 0; c < CD; ++c) znf[c] = znf_s[c][lane];
        const float a2 = a2_s[lane];

        float d1 = 1e30f, d2 = 1e30f, d3 = 1e30f, d4 = 1e30f;
        int i1 = 0, i2 = 0, i3 = 0, i4 = 0;
        {
            const float4* cp = (const float4*)(cbn32 + ((size_t)q * K + (size_t)kc * 256) * CD);
            const float* nq = n232 + q * K + kc * 256;
            for (int k = 0; k < 256; k += 4) {
                const float4* c0 = cp + k * (CD / 4);
                float p0 = 0.f, p1 = 0.f, p2 = 0.f, p3 = 0.f;
                float r0 = 0.f, r1 = 0.f, r2 = 0.f, r3 = 0.f;
                float s0 = 0.f, s1 = 0.f, s2 = 0.f, s3 = 0.f;
                float u0 = 0.f, u1 = 0.f, u2 = 0.f, u3 = 0.f;
#pragma unroll
                for (int u = 0; u < CD / 4; ++u) {
                    float4 av = c0[u];
                    float4 bv = c0[u + 8];
                    float4 cv = c0[u + 16];
                    float4 dv = c0[u + 24];
                    float z0f = znf[u * 4 + 0], z1f = znf[u * 4 + 1];
                    float z2f = znf[u * 4 + 2], z3f = znf[u * 4 + 3];
                    p0 = fmaf(z0f, av.x, p0); p1 = fmaf(z1f, av.y, p1);
                    p2 = fmaf(z2f, av.z, p2); p3 = fmaf(z3f, av.w, p3);
                    r0 = fmaf(z0f, bv.x, r0); r1 = fmaf(z1f, bv.y, r1);
                    r2 = fmaf(z2f, bv.z, r2); r3 = fmaf(z3f, bv.w, r3);
                    s0 = fmaf(z0f, cv.x, s0); s1 = fmaf(z1f, cv.y, s1);
                    s2 = fmaf(z2f, cv.z, s2); s3 = fmaf(z3f, cv.w, s3);
                    u0 = fmaf(z0f, dv.x, u0); u1 = fmaf(z1f, dv.y, u1);
                    u2 = fmaf(z2f, dv.z, u2); u3 = fmaf(z3f, dv.w, u3);
                }
                float dist0 = fmaf(-2.0f, (p0 + p1) + (p2 + p3), a2) + nq[k];
                float dist1 = fmaf(-2.0f, (r0 + r1) + (r2 + r3), a2) + nq[k + 1];
                float dist2 = fmaf(-2.0f, (s0 + s1) + (s2 + s3), a2) + nq[k + 2];
                float dist3 = fmaf(-2.0f, (u0 + u1) + (u2 + u3), a2) + nq[k + 3];
                INS4(dist0, kc * 256 + k);
                INS4(dist1, kc * 256 + k + 1);
                INS4(dist2, kc * 256 + k + 2);
                INS4(dist3, kc * 256 + k + 3);
            }
        }
        sd[kc_v][0][lane] = d1; sd[kc_v][1][lane] = d2;
        sd[kc_v][2][lane] = d3; sd[kc_v][3][lane] = d4;
        si[kc_v][0][lane] = i1; si[kc_v][1][lane] = i2;
        si[kc_v][2][lane] = i3; si[kc_v][3][lane] = i4;
        __syncthreads();

        // ---- wave 0: merge 16 -> top-4, gate, fp64 decide, outputs ----
        if (kc_v == 0) {
            d1 = d2 = d3 = d4 = 1e30f; i1 = i2 = i3 = i4 = 0;
#pragma unroll
            for (int w = 0; w < 4; ++w)
#pragma unroll
                for (int s4 = 0; s4 < 4; ++s4)
                    INS4(sd[w][s4][lane], si[w][s4][lane]);

            int bi;
            if (d4 - d1 >= 1e-4f) {
                // winner provably among {i1..i4}; fp64 eval, index-ascending
                int j1 = i1, j2 = i2, j3 = i3, j4 = i4;
                { int tt; if (j1 > j2) { tt = j1; j1 = j2; j2 = tt; }
                          if (j3 > j4) { tt = j3; j3 = j4; j4 = tt; }
                          if (j1 > j3) { tt = j1; j1 = j3; j3 = tt; }
                          if (j2 > j4) { tt = j2; j2 = j4; j4 = tt; }
                          if (j2 > j3) { tt = j2; j2 = j3; j3 = tt; } }
                const double* cq64 = cbn64 + (size_t)q * K * CD;
                const double* nq64 = n264 + (size_t)q * K;
                double dot1v = 0.0, dot2v = 0.0, dot3v = 0.0, dot4v = 0.0;
                const double* r1p = cq64 + (size_t)j1 * CD;
                const double* r2p = cq64 + (size_t)j2 * CD;
                const double* r3p = cq64 + (size_t)j3 * CD;
                const double* r4p = cq64 + (size_t)j4 * CD;
#pragma unroll
                for (int c = 0; c < CD; ++c) {
                    dot1v = fma(zn[c], r1p[c], dot1v);
                    dot2v = fma(zn[c], r2p[c], dot2v);
                    dot3v = fma(zn[c], r3p[c], dot3v);
                    dot4v = fma(zn[c], r4p[c], dot4v);
                }
                double e1 = (A - 2.0 * dot1v) + nq64[j1];
                double e2 = (A - 2.0 * dot2v) + nq64[j2];
                double e3 = (A - 2.0 * dot3v) + nq64[j3];
                double e4 = (A - 2.0 * dot4v) + nq64[j4];
                double best = e1; bi = j1;
                if (e2 < best) { best = e2; bi = j2; }
                if (e3 < best) { best = e3; bi = j3; }
                if (e4 < best) { best = e4; bi = j4; }
            } else {
                // rare full fp64 rescan (exact round-1 formula; 2-code ILP)
                double best = 1e300; bi = 0;
                const double* cq64 = cbn64 + (size_t)q * K * CD;
                const double* nq64 = n264 + (size_t)q * K;
                for (int k = 0; k < K; k += 2) {
                    double dot0 = 0.0, dot1 = 0.0;
                    const double* c0 = cq64 + (size_t)k * CD;
                    const double* c1 = c0 + CD;
#pragma unroll
                    for (int c = 0; c < CD; ++c) {
                        dot0 = fma(zn[c], c0[c], dot0);
                        dot1 = fma(zn[c], c1[c], dot1);
                    }
                    double dist0 = (A - 2.0 * dot0) + nq64[k];
                    double dist1 = (A - 2.0 * dot1) + nq64[k + 1];
                    if (dist0 < best) { best = dist0; bi = k; }
                    if (dist1 < best) { best = dist1; bi = k + 1; }
                }
            }
            hist[q] = bi;

            const float* cr = cb + ((size_t)q * K + bi) * CD;
            double sq = 0.0;
#pragma unroll
            for (int c = 0; c < CD; ++c) {
                double diff = zn[c] * rnorm - (double)cr[c];   // round-1 loss form
                sq = fma(diff, diff, sq);
            }
#pragma unroll
            for (int off = 32; off > 0; off >>= 1) sq += __shfl_down(sq, off);
            if (lane == 0)
                atomicAdd(&loss[q], (float)(sq * (1.25 / (double)((size_t)B * CD * T))));
            idxi[q * BT + bt] = bi;
            idx_f[(size_t)q * BT + bt] = (float)bi;
        }
        __syncthreads();   // WAR: sd/si + znf_s reused next stage
    }
}

// ---------- k_final as register-blocked fp32 GEMM ----------
#define GT 128
#define GD 128
__global__ __launch_bounds__(256) void k_gemm_final(const float* __restrict__ Wout,
                                                    const float* __restrict__ bo,
                                                    const float* __restrict__ cb,
                                                    const int* __restrict__ idxi,
                                                    float* __restrict__ out) {
    const int t0 = blockIdx.x * GT;
    const int b  = blockIdx.y;
    const int d0 = blockIdx.z * GD;
    const int tx = threadIdx.x & 15;
    const int ty = threadIdx.x >> 4;
    __shared__ float Wt[CD][GD + 4];
    __shared__ float Zt[CD][GT + 4];
    __shared__ float bsum[GD];

    if (threadIdx.x < GD) {
        float sjb = 0.0f;
#pragma unroll
        for (int j = 0; j < Q; ++j) sjb += bo[j * D + d0 + threadIdx.x];
        bsum[threadIdx.x] = sjb;
    }

    float acc[8][8];
#pragma unroll
    for (int r = 0; r < 8; ++r)
#pragma unroll
        for (int cc = 0; cc < 8; ++cc) acc[r][cc] = 0.0f;

    for (int j = 0; j < Q; ++j) {
        __syncthreads();   // WAR on Wt/Zt
        for (int i = threadIdx.x; i < GD * CD; i += 256) {
            int dl = i >> 5, c = i & 31;
            Wt[c][dl] = Wout[((size_t)j * D + d0 + dl) * CD + c];
        }
        for (int i = threadIdx.x; i < GT * CD; i += 256) {
            int tl = i >> 5, c = i & 31;
            int kj = idxi[j * BT + (size_t)b * T + t0 + tl];
            Zt[c][tl] = cb[((size_t)j * K + kj) * CD + c];
        }
        __syncthreads();
#pragma unroll
        for (int k = 0; k < CD; ++k) {
            float a[8], zb[8];
            *(float4*)&a[0]  = *(const float4*)&Wt[k][ty * 8];
            *(float4*)&a[4]  = *(const float4*)&Wt[k][ty * 8 + 4];
            *(float4*)&zb[0] = *(const float4*)&Zt[k][tx * 8];
            *(float4*)&zb[4] = *(const float4*)&Zt[k][tx * 8 + 4];
#pragma unroll
            for (int r = 0; r < 8; ++r)
#pragma unroll
                for (int cc = 0; cc < 8; ++cc)
                    acc[r][cc] = fmaf(a[r], zb[cc], acc[r][cc]);
        }
    }
#pragma unroll
    for (int r = 0; r < 8; ++r) {
        const int d = d0 + ty * 8 + r;
        const float bias = bsum[ty * 8 + r];
        float4 v0, v1;
        v0.x = acc[r][0] + bias; v0.y = acc[r][1] + bias;
        v0.z = acc[r][2] + bias; v0.w = acc[r][3] + bias;
        v1.x = acc[r][4] + bias; v1.y = acc[r][5] + bias;
        v1.z = acc[r][6] + bias; v1.w = acc[r][7] + bias;
        float* op = out + ((size_t)b * D + d) * T + t0 + tx * 8;
        *(float4*)op = v0;
        *(float4*)(op + 4) = v1;
    }
}

extern "C" void kernel_launch(void* const* d_in, const int* in_sizes, int n_in,
                              void* d_out, int out_size, void* d_ws, size_t ws_size,
                              hipStream_t stream) {
    const float* x     = (const float*)d_in[0];
    const float* Win   = (const float*)d_in[1];
    const float* b_in  = (const float*)d_in[2];
    const float* Wout  = (const float*)d_in[3];
    const float* b_out = (const float*)d_in[4];
    const float* cb    = (const float*)d_in[5];

    float* out0  = (float*)d_out;
    float* idx_f = out0 + (size_t)B * D * T;
    float* loss  = idx_f + (size_t)Q * BT;

    char* sc = (char*)d_out;   // scratch: dead before k_gemm_final writes out0
    double* z0    = (double*)(sc + OFF_Z0);
    double* Mt    = (double*)(sc + OFF_MT);
    double* cbn64 = (double*)(sc + OFF_CBN);
    double* n264  = (double*)(sc + OFF_N264);
    double* Ntab  = (double*)(sc + OFF_NT);
    double* beff  = (double*)(sc + OFF_BEFF);
    float*  cbn32 = (float*)(sc + OFF_C32);
    float*  n232  = (float*)(sc + OFF_N232);
    double* Win64 = (double*)(sc + OFF_W64);
    int*    idxi  = (int*)d_ws;                  // 1 MB, safe for gemm_final

    k_zero_losses<<<1, 64, 0, stream>>>(loss);
    k_norm<<<(Q * K) / 256, 256, 0, stream>>>(cb, cbn64, n264, cbn32, n232);
    k_cvtW<<<(Q * CD * D) / 256, 256, 0, stream>>>(Win, Win64);
    k_prep_N<<<64, 256, 0, stream>>>(Win, Wout, Ntab);
    k_prep_M<<<dim3(K / 256, 8, 8), 256, 0, stream>>>(cb, Ntab, Mt);
    k_prep_beff<<<dim3(CD, Q), 256, 0, stream>>>(Win, b_in, b_out, beff);

    k_gemmZ<<<Q * B * (T / 256), 256, 0, stream>>>(x, Win64, beff, z0);

    k_argmin_fused<<<dim3(T / AT, B), 256, 0, stream>>>(z0, Mt, cbn64, n264,
                                                        cbn32, n232, cb,
                                                        idxi, idx_f, loss);

    k_gemm_final<<<dim3(T / GT, B, D / GD), 256, 0, stream>>>(Wout, b_out, cb, idxi, out0);
}

// Round 7
// 1476.086 us; speedup vs baseline: 3.7588x; 1.5063x over previous
//
#include <hip/hip_runtime.h>
#include <math.h>

#define B 8
#define D 1024
#define T 4096
#define Q 8
#define K 1024
#define CD 32
#define BT (B * T)

// ---------------- scratch layout inside d_out (bytes) ----------------
// d_out floats [0 .. B*D*T) are scratch until k_gemm_final (last kernel) writes them.
// k_gemm_final reads ONLY inputs + idxi (in d_ws) -> no overlap hazard.
#define OFF_Z0   ((size_t)0)                            // f64 [Q][B][CD][T]  64 MB
#define OFF_MT   (OFF_Z0 + (size_t)Q * B * CD * T * 8)  // f64 [8][8][K][CD]  16 MB
#define OFF_CBN  (OFF_MT + (size_t)64 * K * CD * 8)     // f64 [Q][K][CD]      2 MB
#define OFF_N264 (OFF_CBN + (size_t)Q * K * CD * 8)     // f64 [Q][K]         64 KB
#define OFF_NT   (OFF_N264 + (size_t)Q * K * 8)         // f64 [64][CD][CD]  512 KB
#define OFF_BEFF (OFF_NT + (size_t)64 * CD * CD * 8)    // f64 [Q][CD]         2 KB
#define OFF_C32  (OFF_BEFF + (size_t)Q * CD * 8)        // f32 [Q][K][CD]      1 MB
#define OFF_N232 (OFF_C32 + (size_t)Q * K * CD * 4)     // f32 [Q][K]         32 KB
#define OFF_W64  (OFF_N232 + (size_t)Q * K * 4)         // f64 [Q][CD][D]      2 MB
// idxi i32 [Q][BT] lives in d_ws @ 0 (1 MB)

__global__ void k_zero_losses(float* __restrict__ loss) {
    if (threadIdx.x < Q) loss[threadIdx.x] = 0.0f;
}

// Normalize codebooks fp64 + fp32 copies for the prefilter.
__global__ __launch_bounds__(256) void k_norm(const float* __restrict__ cb,
                                              double* __restrict__ cbn64,
                                              double* __restrict__ n264,
                                              float* __restrict__ cbn32,
                                              float* __restrict__ n232) {
    int i = blockIdx.x * 256 + threadIdx.x;   // 0..Q*K-1
    const float* c = cb + (size_t)i * CD;
    double v[CD];
    double ss = 0.0;
#pragma unroll
    for (int j = 0; j < CD; ++j) { v[j] = (double)c[j]; ss += v[j] * v[j]; }
    double s = 1.0 / sqrt(ss + 1e-12);
    double n2 = 0.0;
    double* o = cbn64 + (size_t)i * CD;
    float* o32 = cbn32 + (size_t)i * CD;
#pragma unroll
    for (int j = 0; j < CD; ++j) {
        double vn = v[j] * s;
        o[j] = vn; o32[j] = (float)vn; n2 += vn * vn;
    }
    n264[i] = n2; n232[i] = (float)n2;
}

// Win -> fp64 copy
__global__ __launch_bounds__(256) void k_cvtW(const float* __restrict__ Win,
                                              double* __restrict__ Win64) {
    int i = blockIdx.x * 256 + threadIdx.x;
    Win64[i] = (double)Win[i];
}

// N[q][j][c][c'] = sum_d Win_q[c,d] * Wout_j[d,c']   (fp64)
__global__ __launch_bounds__(256) void k_prep_N(const float* __restrict__ Win,
                                                const float* __restrict__ Wout,
                                                double* __restrict__ Ntab) {
    const int q = blockIdx.x >> 3, j = blockIdx.x & 7;
    __shared__ float a_sh[CD][128];
    __shared__ float b_sh[128][CD];
    double acc[4] = {0.0, 0.0, 0.0, 0.0};
    for (int d0 = 0; d0 < D; d0 += 128) {
        __syncthreads();
        for (int i = threadIdx.x; i < CD * 128; i += 256) {
            int cc = i >> 7, dl = i & 127;
            a_sh[cc][dl] = Win[((size_t)q * CD + cc) * D + d0 + dl];
        }
        for (int i = threadIdx.x; i < 128 * CD; i += 256) {
            int dl = i >> 5, cc = i & 31;
            b_sh[dl][cc] = Wout[((size_t)j * D + d0 + dl) * CD + cc];
        }
        __syncthreads();
        for (int dl = 0; dl < 128; ++dl) {
#pragma unroll
            for (int r = 0; r < 4; ++r) {
                int i = r * 256 + threadIdx.x;
                acc[r] = fma((double)a_sh[i >> 5][dl], (double)b_sh[dl][i & 31], acc[r]);
            }
        }
    }
#pragma unroll
    for (int r = 0; r < 4; ++r) {
        int i = r * 256 + threadIdx.x;
        Ntab[((size_t)(q * 8 + j) * CD + (i >> 5)) * CD + (i & 31)] = acc[r];
    }
}

// M[q][j][k][c] = sum_c' N[q][j][c][c'] * cb_j[k][c']   (fp64)
__global__ __launch_bounds__(256) void k_prep_M(const float* __restrict__ cb,
                                                const double* __restrict__ Ntab,
                                                double* __restrict__ Mt) {
    const int q = blockIdx.z, j = blockIdx.y;
    const int k = blockIdx.x * 256 + threadIdx.x;
    __shared__ double nsh[CD][CD];
    for (int i = threadIdx.x; i < CD * CD; i += 256)
        nsh[i >> 5][i & 31] = Ntab[(size_t)(q * 8 + j) * CD * CD + i];
    __syncthreads();
    double cv[CD];
    const float* cr = cb + ((size_t)j * K + k) * CD;
#pragma unroll
    for (int c = 0; c < CD; ++c) cv[c] = (double)cr[c];
    double* mo = Mt + (((size_t)(q * 8 + j) * K + k) * CD);
#pragma unroll
    for (int c = 0; c < CD; ++c) {
        double a = 0.0;
#pragma unroll
        for (int cp = 0; cp < CD; ++cp) a = fma(nsh[c][cp], cv[cp], a);
        mo[c] = a;
    }
}

// beff[q][c] = b_in[q][c] - sum_d Win_q[c][d] * (sum_{j<q} b_out[j][d])
__global__ __launch_bounds__(256) void k_prep_beff(const float* __restrict__ Win,
                                                   const float* __restrict__ b_in,
                                                   const float* __restrict__ b_out,
                                                   double* __restrict__ beff) {
    const int c = blockIdx.x, q = blockIdx.y;
    __shared__ double red[256];
    double p = 0.0;
    for (int d = threadIdx.x; d < D; d += 256) {
        double bp = 0.0;
        for (int j = 0; j < q; ++j) bp += (double)b_out[j * D + d];
        p = fma((double)Win[((size_t)q * CD + c) * D + d], bp, p);
    }
    red[threadIdx.x] = p;
    __syncthreads();
    for (int s = 128; s > 0; s >>= 1) {
        if (threadIdx.x < s) red[threadIdx.x] += red[threadIdx.x + s];
        __syncthreads();
    }
    if (threadIdx.x == 0) beff[q * CD + c] = (double)b_in[q * CD + c] - red[0];
}

// z0[q][b][c][t] = beff[q][c] + sum_d Win_q[c][d] * x[b][d][t]  (fp64)
__global__ __launch_bounds__(256) void k_gemmZ(const float* __restrict__ x,
                                               const double* __restrict__ Win64,
                                               const double* __restrict__ beff,
                                               double* __restrict__ z0) {
    int h = blockIdx.x;
    int u = h >> 3, r = h & 7;
    int q = u & 7;
    int m = r + 8 * (u >> 3);
    int b = m >> 4;
    int tc = m & 15;
    int t = tc * 256 + threadIdx.x;

    const double* w = Win64 + (size_t)q * CD * D;
    const double* be = beff + q * CD;
    const float* xb = x + (size_t)b * D * T + t;

    double acc[CD];
#pragma unroll
    for (int c = 0; c < CD; ++c) acc[c] = be[c];

    for (int d0 = 0; d0 < D; d0 += 8) {
        double xv[8];
#pragma unroll
        for (int i = 0; i < 8; ++i) xv[i] = (double)xb[(size_t)(d0 + i) * T];
#pragma unroll
        for (int c = 0; c < CD; ++c) {
            const double* wc = w + (size_t)c * D + d0;
#pragma unroll
            for (int i = 0; i < 8; ++i) acc[c] = fma(wc[i], xv[i], acc[c]);
        }
    }
    double* zo = z0 + (((size_t)q * B + b) * CD) * T + t;
#pragma unroll
    for (int c = 0; c < CD; ++c) zo[(size_t)c * T] = acc[c];
}

// insert (dd,ii) into sorted top-4 (d1<=d2<=d3<=d4)
#define INS4(dd, ii)                                                           \
    do {                                                                       \
        float _d = (dd); int _i = (ii);                                        \
        if (_d < d4) {                                                         \
            d4 = _d; i4 = _i;                                                  \
            if (d4 < d3) { float tf = d3; d3 = d4; d4 = tf; int ti = i3; i3 = i4; i4 = ti; } \
            if (d3 < d2) { float tf = d2; d2 = d3; d3 = tf; int ti = i2; i2 = i3; i3 = ti; } \
            if (d2 < d1) { float tf = d1; d1 = d2; d2 = tf; int ti = i1; i1 = i2; i2 = ti; } \
        }                                                                      \
    } while (0)

// ---------- fused 8-stage argmin, 16-wave blocks ----------
// 1024 thr = 16 waves, 64 t per block (lane = t). K split 16 x 64 codes.
// Phase A (all 16 waves): wave w reconstructs channels {2w,2w+1} of z -> zn_s (fp64 LDS).
// Phase B (wave 0): serial-order norm (bit-identical to rounds 1-6); publish znf/a2.
// Phase C (all): fp32 top-4 scan of own 64-code slice (same per-code arithmetic).
// Phase C2 (waves 0-3): tree merge 16 lists -> 4.
// Phase D (wave 0): final merge, gate, fp64 candidate eval / rare rescan, loss, writes.
#define AT 64
__global__ __launch_bounds__(1024) void k_argmin_fused(const double* __restrict__ z0,
                                                       const double* __restrict__ Mt,
                                                       const double* __restrict__ cbn64,
                                                       const double* __restrict__ n264,
                                                       const float* __restrict__ cbn32,
                                                       const float* __restrict__ n232,
                                                       const float* __restrict__ cb,
                                                       int* __restrict__ idxi,
                                                       float* __restrict__ idx_f,
                                                       float* __restrict__ loss) {
    const int lane = threadIdx.x & 63;
    const int wv = threadIdx.x >> 6;                        // 0..15
    const int kcw = __builtin_amdgcn_readfirstlane(wv);     // uniform wave id
    const int t = blockIdx.x * AT + lane;
    const int b = blockIdx.y;
    const size_t bt = (size_t)b * T + t;

    __shared__ double zn_s[CD][AT];     // 16 KB (normalized z, fp64)
    __shared__ float  znf_s[CD][AT];    //  8 KB
    __shared__ float  a2_s[AT];
    __shared__ double rn_s[AT];
    __shared__ float  sd[16][4][AT];    // 16 KB
    __shared__ int    si[16][4][AT];    // 16 KB
    __shared__ int    hist_s[Q][AT];    //  2 KB

    for (int q = 0; q < Q; ++q) {
        // ---- Phase A: distributed reconstruct (exact j-ascending chain per channel) ----
        {
            const int c0 = wv * 2;
            double v0 = z0[(((size_t)q * B + b) * CD + c0) * T + t];
            double v1 = z0[(((size_t)q * B + b) * CD + c0 + 1) * T + t];
            for (int j = 0; j < q; ++j) {
                int kj = hist_s[j][lane];
                const double* m = Mt + (((size_t)(q * 8 + j) * K + kj) * CD);
                v0 -= m[c0];
                v1 -= m[c0 + 1];
            }
            zn_s[c0][lane] = v0;
            zn_s[c0 + 1][lane] = v1;
        }
        __syncthreads();

        // ---- Phase B: wave 0 serial-order normalize (bit-identical to round 5/6) ----
        if (wv == 0) {
            double ss = 0.0;
#pragma unroll
            for (int c = 0; c < CD; ++c) { double v = zn_s[c][lane]; ss += v * v; }
            double rnorm = sqrt(ss + 1e-12);
            double s = 1.0 / rnorm;
            float a2 = 0.0f;
#pragma unroll
            for (int c = 0; c < CD; ++c) {
                double vn = zn_s[c][lane] * s;
                zn_s[c][lane] = vn;
                float zf = (float)vn;
                znf_s[c][lane] = zf;
                a2 = fmaf(zf, zf, a2);
            }
            a2_s[lane] = a2;
            rn_s[lane] = rnorm;
        }
        __syncthreads();

        // ---- Phase C: fp32 top-4 scan of own 64-code slice, 4 codes/iter ----
        {
            float znf[CD];
#pragma unroll
            for (int c = 0; c < CD; ++c) znf[c] = znf_s[c][lane];
            const float a2 = a2_s[lane];

            float d1 = 1e30f, d2 = 1e30f, d3 = 1e30f, d4 = 1e30f;
            int i1 = 0, i2 = 0, i3 = 0, i4 = 0;
            const float4* cp = (const float4*)(cbn32 + ((size_t)q * K + (size_t)kcw * 64) * CD);
            const float* nq = n232 + q * K + kcw * 64;
            for (int k = 0; k < 64; k += 4) {
                const float4* c0 = cp + k * (CD / 4);
                float p0 = 0.f, p1 = 0.f, p2 = 0.f, p3 = 0.f;
                float r0 = 0.f, r1 = 0.f, r2 = 0.f, r3 = 0.f;
                float s0 = 0.f, s1 = 0.f, s2 = 0.f, s3 = 0.f;
                float u0 = 0.f, u1 = 0.f, u2 = 0.f, u3 = 0.f;
#pragma unroll
                for (int u = 0; u < CD / 4; ++u) {
                    float4 av = c0[u];
                    float4 bv = c0[u + 8];
                    float4 cv = c0[u + 16];
                    float4 dv = c0[u + 24];
                    float z0f = znf[u * 4 + 0], z1f = znf[u * 4 + 1];
                    float z2f = znf[u * 4 + 2], z3f = znf[u * 4 + 3];
                    p0 = fmaf(z0f, av.x, p0); p1 = fmaf(z1f, av.y, p1);
                    p2 = fmaf(z2f, av.z, p2); p3 = fmaf(z3f, av.w, p3);
                    r0 = fmaf(z0f, bv.x, r0); r1 = fmaf(z1f, bv.y, r1);
                    r2 = fmaf(z2f, bv.z, r2); r3 = fmaf(z3f, bv.w, r3);
                    s0 = fmaf(z0f, cv.x, s0); s1 = fmaf(z1f, cv.y, s1);
                    s2 = fmaf(z2f, cv.z, s2); s3 = fmaf(z3f, cv.w, s3);
                    u0 = fmaf(z0f, dv.x, u0); u1 = fmaf(z1f, dv.y, u1);
                    u2 = fmaf(z2f, dv.z, u2); u3 = fmaf(z3f, dv.w, u3);
                }
                float dist0 = fmaf(-2.0f, (p0 + p1) + (p2 + p3), a2) + nq[k];
                float dist1 = fmaf(-2.0f, (r0 + r1) + (r2 + r3), a2) + nq[k + 1];
                float dist2 = fmaf(-2.0f, (s0 + s1) + (s2 + s3), a2) + nq[k + 2];
                float dist3 = fmaf(-2.0f, (u0 + u1) + (u2 + u3), a2) + nq[k + 3];
                INS4(dist0, kcw * 64 + k);
                INS4(dist1, kcw * 64 + k + 1);
                INS4(dist2, kcw * 64 + k + 2);
                INS4(dist3, kcw * 64 + k + 3);
            }
            sd[wv][0][lane] = d1; sd[wv][1][lane] = d2;
            sd[wv][2][lane] = d3; sd[wv][3][lane] = d4;
            si[wv][0][lane] = i1; si[wv][1][lane] = i2;
            si[wv][2][lane] = i3; si[wv][3][lane] = i4;
        }
        __syncthreads();

        // ---- Phase C2: waves 0..3 tree-merge lists {w, w+4, w+8, w+12} ----
        if (wv < 4) {
            float d1 = 1e30f, d2 = 1e30f, d3 = 1e30f, d4 = 1e30f;
            int i1 = 0, i2 = 0, i3 = 0, i4 = 0;
            for (int w = wv; w < 16; w += 4)
#pragma unroll
                for (int s4 = 0; s4 < 4; ++s4)
                    INS4(sd[w][s4][lane], si[w][s4][lane]);
            sd[wv][0][lane] = d1; sd[wv][1][lane] = d2;
            sd[wv][2][lane] = d3; sd[wv][3][lane] = d4;
            si[wv][0][lane] = i1; si[wv][1][lane] = i2;
            si[wv][2][lane] = i3; si[wv][3][lane] = i4;
        }
        __syncthreads();

        // ---- Phase D: wave 0 final merge + gate + fp64 decide + outputs ----
        if (wv == 0) {
            float d1 = 1e30f, d2 = 1e30f, d3 = 1e30f, d4 = 1e30f;
            int i1 = 0, i2 = 0, i3 = 0, i4 = 0;
#pragma unroll
            for (int w = 0; w < 4; ++w)
#pragma unroll
                for (int s4 = 0; s4 < 4; ++s4)
                    INS4(sd[w][s4][lane], si[w][s4][lane]);

            const double rnorm = rn_s[lane];
            int bi;
            if (d4 - d1 >= 1e-4f) {
                // winner provably among {i1..i4}; fp64 eval, index-ascending
                int j1 = i1, j2 = i2, j3 = i3, j4 = i4;
                { int tt; if (j1 > j2) { tt = j1; j1 = j2; j2 = tt; }
                          if (j3 > j4) { tt = j3; j3 = j4; j4 = tt; }
                          if (j1 > j3) { tt = j1; j1 = j3; j3 = tt; }
                          if (j2 > j4) { tt = j2; j2 = j4; j4 = tt; }
                          if (j2 > j3) { tt = j2; j2 = j3; j3 = tt; } }
                const double* cq64 = cbn64 + (size_t)q * K * CD;
                const double* nq64 = n264 + (size_t)q * K;
                double dot1v = 0.0, dot2v = 0.0, dot3v = 0.0, dot4v = 0.0;
                double A = 0.0;
                const double* r1p = cq64 + (size_t)j1 * CD;
                const double* r2p = cq64 + (size_t)j2 * CD;
                const double* r3p = cq64 + (size_t)j3 * CD;
                const double* r4p = cq64 + (size_t)j4 * CD;
#pragma unroll
                for (int c = 0; c < CD; ++c) {
                    double vn = zn_s[c][lane];
                    A += vn * vn;                    // round-5 A order (post-normalize sq-sum)
                    dot1v = fma(vn, r1p[c], dot1v);
                    dot2v = fma(vn, r2p[c], dot2v);
                    dot3v = fma(vn, r3p[c], dot3v);
                    dot4v = fma(vn, r4p[c], dot4v);
                }
                double e1 = (A - 2.0 * dot1v) + nq64[j1];
                double e2 = (A - 2.0 * dot2v) + nq64[j2];
                double e3 = (A - 2.0 * dot3v) + nq64[j3];
                double e4 = (A - 2.0 * dot4v) + nq64[j4];
                double best = e1; bi = j1;
                if (e2 < best) { best = e2; bi = j2; }
                if (e3 < best) { best = e3; bi = j3; }
                if (e4 < best) { best = e4; bi = j4; }
            } else {
                // rare full fp64 rescan (exact round-1 formula; 2-code ILP)
                double zn[CD]; double A = 0.0;
#pragma unroll
                for (int c = 0; c < CD; ++c) { zn[c] = zn_s[c][lane]; A += zn[c] * zn[c]; }
                double best = 1e300; bi = 0;
                const double* cq64 = cbn64 + (size_t)q * K * CD;
                const double* nq64 = n264 + (size_t)q * K;
                for (int k = 0; k < K; k += 2) {
                    double dot0 = 0.0, dot1 = 0.0;
                    const double* c0 = cq64 + (size_t)k * CD;
                    const double* c1 = c0 + CD;
#pragma unroll
                    for (int c = 0; c < CD; ++c) {
                        dot0 = fma(zn[c], c0[c], dot0);
                        dot1 = fma(zn[c], c1[c], dot1);
                    }
                    double dist0 = (A - 2.0 * dot0) + nq64[k];
                    double dist1 = (A - 2.0 * dot1) + nq64[k + 1];
                    if (dist0 < best) { best = dist0; bi = k; }
                    if (dist1 < best) { best = dist1; bi = k + 1; }
                }
            }
            hist_s[q][lane] = bi;

            const float* cr = cb + ((size_t)q * K + bi) * CD;
            double sq = 0.0;
#pragma unroll
            for (int c = 0; c < CD; ++c) {
                double diff = zn_s[c][lane] * rnorm - (double)cr[c];   // round-1 loss form
                sq = fma(diff, diff, sq);
            }
#pragma unroll
            for (int off = 32; off > 0; off >>= 1) sq += __shfl_down(sq, off);
            if (lane == 0)
                atomicAdd(&loss[q], (float)(sq * (1.25 / (double)((size_t)B * CD * T))));
            idxi[q * BT + bt] = bi;
            idx_f[(size_t)q * BT + bt] = (float)bi;
        }
        __syncthreads();   // WAR: zn_s/sd/si reused next stage; hist_s visible to Phase A
    }
}

// ---------- k_final as register-blocked fp32 GEMM ----------
#define GT 128
#define GD 128
__global__ __launch_bounds__(256) void k_gemm_final(const float* __restrict__ Wout,
                                                    const float* __restrict__ bo,
                                                    const float* __restrict__ cb,
                                                    const int* __restrict__ idxi,
                                                    float* __restrict__ out) {
    const int t0 = blockIdx.x * GT;
    const int b  = blockIdx.y;
    const int d0 = blockIdx.z * GD;
    const int tx = threadIdx.x & 15;
    const int ty = threadIdx.x >> 4;
    __shared__ float Wt[CD][GD + 4];
    __shared__ float Zt[CD][GT + 4];
    __shared__ float bsum[GD];

    if (threadIdx.x < GD) {
        float sjb = 0.0f;
#pragma unroll
        for (int j = 0; j < Q; ++j) sjb += bo[j * D + d0 + threadIdx.x];
        bsum[threadIdx.x] = sjb;
    }

    float acc[8][8];
#pragma unroll
    for (int r = 0; r < 8; ++r)
#pragma unroll
        for (int cc = 0; cc < 8; ++cc) acc[r][cc] = 0.0f;

    for (int j = 0; j < Q; ++j) {
        __syncthreads();   // WAR on Wt/Zt
        for (int i = threadIdx.x; i < GD * CD; i += 256) {
            int dl = i >> 5, c = i & 31;
            Wt[c][dl] = Wout[((size_t)j * D + d0 + dl) * CD + c];
        }
        for (int i = threadIdx.x; i < GT * CD; i += 256) {
            int tl = i >> 5, c = i & 31;
            int kj = idxi[j * BT + (size_t)b * T + t0 + tl];
            Zt[c][tl] = cb[((size_t)j * K + kj) * CD + c];
        }
        __syncthreads();
#pragma unroll
        for (int k = 0; k < CD; ++k) {
            float a[8], zb[8];
            *(float4*)&a[0]  = *(const float4*)&Wt[k][ty * 8];
            *(float4*)&a[4]  = *(const float4*)&Wt[k][ty * 8 + 4];
            *(float4*)&zb[0] = *(const float4*)&Zt[k][tx * 8];
            *(float4*)&zb[4] = *(const float4*)&Zt[k][tx * 8 + 4];
#pragma unroll
            for (int r = 0; r < 8; ++r)
#pragma unroll
                for (int cc = 0; cc < 8; ++cc)
                    acc[r][cc] = fmaf(a[r], zb[cc], acc[r][cc]);
        }
    }
#pragma unroll
    for (int r = 0; r < 8; ++r) {
        const int d = d0 + ty * 8 + r;
        const float bias = bsum[ty * 8 + r];
        float4 v0, v1;
        v0.x = acc[r][0] + bias; v0.y = acc[r][1] + bias;
        v0.z = acc[r][2] + bias; v0.w = acc[r][3] + bias;
        v1.x = acc[r][4] + bias; v1.y = acc[r][5] + bias;
        v1.z = acc[r][6] + bias; v1.w = acc[r][7] + bias;
        float* op = out + ((size_t)b * D + d) * T + t0 + tx * 8;
        *(float4*)op = v0;
        *(float4*)(op + 4) = v1;
    }
}

extern "C" void kernel_launch(void* const* d_in, const int* in_sizes, int n_in,
                              void* d_out, int out_size, void* d_ws, size_t ws_size,
                              hipStream_t stream) {
    const float* x     = (const float*)d_in[0];
    const float* Win   = (const float*)d_in[1];
    const float* b_in  = (const float*)d_in[2];
    const float* Wout  = (const float*)d_in[3];
    const float* b_out = (const float*)d_in[4];
    const float* cb    = (const float*)d_in[5];

    float* out0  = (float*)d_out;
    float* idx_f = out0 + (size_t)B * D * T;
    float* loss  = idx_f + (size_t)Q * BT;

    char* sc = (char*)d_out;   // scratch: dead before k_gemm_final writes out0
    double* z0    = (double*)(sc + OFF_Z0);
    double* Mt    = (double*)(sc + OFF_MT);
    double* cbn64 = (double*)(sc + OFF_CBN);
    double* n264  = (double*)(sc + OFF_N264);
    double* Ntab  = (double*)(sc + OFF_NT);
    double* beff  = (double*)(sc + OFF_BEFF);
    float*  cbn32 = (float*)(sc + OFF_C32);
    float*  n232  = (float*)(sc + OFF_N232);
    double* Win64 = (double*)(sc + OFF_W64);
    int*    idxi  = (int*)d_ws;                  // 1 MB, safe for gemm_final

    k_zero_losses<<<1, 64, 0, stream>>>(loss);
    k_norm<<<(Q * K) / 256, 256, 0, stream>>>(cb, cbn64, n264, cbn32, n232);
    k_cvtW<<<(Q * CD * D) / 256, 256, 0, stream>>>(Win, Win64);
    k_prep_N<<<64, 256, 0, stream>>>(Win, Wout, Ntab);
    k_prep_M<<<dim3(K / 256, 8, 8), 256, 0, stream>>>(cb, Ntab, Mt);
    k_prep_beff<<<dim3(CD, Q), 256, 0, stream>>>(Win, b_in, b_out, beff);

    k_gemmZ<<<Q * B * (T / 256), 256, 0, stream>>>(x, Win64, beff, z0);

    k_argmin_fused<<<dim3(T / AT, B), 1024, 0, stream>>>(z0, Mt, cbn64, n264,
                                                         cbn32, n232, cb,
                                                         idxi, idx_f, loss);

    k_gemm_final<<<dim3(T / GT, B, D / GD), 256, 0, stream>>>(Wout, b_out, cb, idxi, out0);
}